// Round 18
// baseline (2906.437 us; speedup 1.0000x reference)
//
#include <hip/hip_runtime.h>
#include <math.h>

#define BB 8
#define NN 2048
#define KK 20
#define OCH 2564
#define OCN ((size_t)OCH*NN)
#define EPSD 1e-5
#define SLOPED 0.2
#define TS 64

// ---------------- ws layout (float offsets) — ALL DISJOINT while alive ----
// y5 (B*1024*N = 16,777,216 f32) overlays YMX/YMN/U at layer 5 (all dead; ends before V).
#define WS_YMX  ((size_t)4194304)
#define WS_YMN  ((size_t)8404992)
#define WS_U    ((size_t)12615680)
#define WS_V    ((size_t)16826368)
#define WS_IDX  ((size_t)21037056)
#define WS_XX   ((size_t)21364736)
#define WS_WTF  ((size_t)21381120)   // 45376 floats, per-layer offsets {0,192,4288,12480}
#define WS_WTD  ((size_t)21426496)   // 45376
#define WS_W5T  ((size_t)21471872)   // 525312
#define WS_Y5   ((size_t)0)
#define WS_S1   ((size_t)21997184)   // 1024 doubles
#define WS_S2   (WS_S1 + 2048)
#define WS_SC   (WS_S2 + 2048)       // 1024 doubles (layer-5 scale)
#define WS_SH   (WS_SC + 2048)

static inline int cdiv(int a, int b){ return (a+b-1)/b; }

// out[b, 2048+c, n] = xyz[b,n,c]  (features live in `out`; no separate copies)
__global__ void k_prep_x0(const float* __restrict__ xyz, float* __restrict__ out){
  int id = blockIdx.x*256 + threadIdx.x;
  if (id >= BB*NN) return;
  int b = id / NN, n = id % NN;
  const float* p = xyz + ((size_t)b*NN + n)*3;
  float* o = out + (size_t)b*OCN + (size_t)2048*NN + n;
  o[0] = p[0]; o[(size_t)NN] = p[1]; o[2*(size_t)NN] = p[2];
}

// one-shot weight transpose for all 5 layers
__global__ void k_wt_all(const float* __restrict__ W1, const float* __restrict__ W2,
                         const float* __restrict__ W3, const float* __restrict__ W4,
                         const float* __restrict__ W5,
                         float* __restrict__ wtf, float* __restrict__ wtd,
                         float* __restrict__ w5t){
  int id = blockIdx.x*256 + threadIdx.x;
  if (id < 513*1024){
    int c = id / 1024, o = id % 1024;
    w5t[(size_t)c*1024 + o] = W5[(size_t)o*513 + c];
  }
  if (id < 45376){
    const float* W; int C, O; int base;
    if (id < 192)        { W = W1; C = 3;   O = 64;  base = 0; }
    else if (id < 4288)  { W = W2; C = 64;  O = 64;  base = 192; }
    else if (id < 12480) { W = W3; C = 64;  O = 128; base = 4288; }
    else                 { W = W4; C = 128; O = 257; base = 12480; }
    int r = id - base;
    int c = r / O, o = r % O;
    float wf = W[(size_t)o*(2*C) + c];
    float wc = W[(size_t)o*(2*C) + C + c];
    wtf[base + (size_t)c*O + o] = wf;
    wtd[base + (size_t)c*O + o] = wc - wf;
  }
}

// ---- KNN arithmetic: per-output chains validated round 8 (canonical f32) ----
// block (0,0) zeroes s1/s2 for this layer
__global__ void k_xx32(const float* __restrict__ x, int C, size_t bs, float* __restrict__ xx,
                       double* __restrict__ s1, double* __restrict__ s2){
  if (blockIdx.x == 0 && blockIdx.y == 0){
    int t = threadIdx.x;
    #pragma unroll
    for (int i=0;i<4;i++){ s1[t*4+i] = 0.0; s2[t*4+i] = 0.0; }
  }
  int b = blockIdx.y;
  int n = blockIdx.x*256 + threadIdx.x;
  const float* p = x + (size_t)b*bs + n;
  float a;
  if (C <= 8){
    a = 0.f;
    for (int c = 0; c < C; c++){ float v = p[(size_t)c*NN]; float s = v*v; a = a + s; }
  } else {
    float r0,r1,r2,r3,r4,r5,r6,r7;
    { float v;
      v = p[0];            r0 = v*v;
      v = p[(size_t)1*NN]; r1 = v*v;
      v = p[(size_t)2*NN]; r2 = v*v;
      v = p[(size_t)3*NN]; r3 = v*v;
      v = p[(size_t)4*NN]; r4 = v*v;
      v = p[(size_t)5*NN]; r5 = v*v;
      v = p[(size_t)6*NN]; r6 = v*v;
      v = p[(size_t)7*NN]; r7 = v*v;
    }
    for (int i = 8; i < C; i += 8){
      float v;
      v = p[(size_t)(i+0)*NN]; r0 = r0 + v*v;
      v = p[(size_t)(i+1)*NN]; r1 = r1 + v*v;
      v = p[(size_t)(i+2)*NN]; r2 = r2 + v*v;
      v = p[(size_t)(i+3)*NN]; r3 = r3 + v*v;
      v = p[(size_t)(i+4)*NN]; r4 = r4 + v*v;
      v = p[(size_t)(i+5)*NN]; r5 = r5 + v*v;
      v = p[(size_t)(i+6)*NN]; r6 = r6 + v*v;
      v = p[(size_t)(i+7)*NN]; r7 = r7 + v*v;
    }
    a = ((r0+r1)+(r2+r3)) + ((r4+r5)+(r6+r7));
  }
  xx[b*NN + n] = a;
}

// FUSED pd + top-20 (no pd materialization).
// Block = 32 rows of one batch, full 2048-column scan.
// pd values: EXACT validated fmaf chain (c ascending, chunks of 8, zero-pad
// no-ops, (2f*acc - xx[n]) - xx[m]).  Per-thread top-20 insertion over
// ascending-m candidates (validated code), then 8-lane argmax extraction
// (val desc, tie -> lower index; validated comparator) => idx bit-identical.
__global__ __launch_bounds__(256) void k_pdtopk(
    const float* __restrict__ x, int C, size_t bs,
    const float* __restrict__ xx, int* __restrict__ idx){
  __shared__ float As[128][32];   // [Cpad][row], zero-padded
  __shared__ float Bs[8][256];
  int b = blockIdx.y;
  int r0 = blockIdx.x * 32;
  int tid = threadIdx.x;
  int row = tid >> 3;             // 0..31
  int mc  = tid & 7;              // 0..7 : owns cols {m: m%32 in [mc*4, mc*4+4)}
  const float* xb = x + (size_t)b*bs;
  const float* xxb = xx + b*NN;
  int Cpad = (C + 7) & ~7;
  for (int t2 = tid; t2 < Cpad*32; t2 += 256){
    int c = t2 >> 5, r = t2 & 31;
    As[c][r] = (c < C) ? xb[(size_t)c*NN + r0 + r] : 0.f;
  }
  __syncthreads();
  float xn = xxb[r0 + row];
  float vals[KK]; int inds[KK];
  #pragma unroll
  for (int i=0;i<KK;i++){ vals[i] = -INFINITY; inds[i] = NN; }
  for (int mb = 0; mb < 8; mb++){
    int mbase = mb*256;
    float acc[8][4];
    #pragma unroll
    for (int q=0;q<8;q++){
      #pragma unroll
      for (int e=0;e<4;e++) acc[q][e] = 0.f;
    }
    for (int c0 = 0; c0 < C; c0 += 8){
      #pragma unroll
      for (int rr=0; rr<8; rr++){
        int t2 = tid + rr*256;
        int c = t2 >> 8, col = t2 & 255;
        int cc = c0 + c;
        Bs[c][col] = (cc < C) ? xb[(size_t)cc*NN + mbase + col] : 0.f;
      }
      __syncthreads();
      #pragma unroll
      for (int c=0;c<8;c++){
        float a = As[c0+c][row];
        #pragma unroll
        for (int q=0;q<8;q++){
          float4 bq = *reinterpret_cast<const float4*>(&Bs[c][q*32 + mc*4]);
          acc[q][0] = fmaf(a, bq.x, acc[q][0]);
          acc[q][1] = fmaf(a, bq.y, acc[q][1]);
          acc[q][2] = fmaf(a, bq.z, acc[q][2]);
          acc[q][3] = fmaf(a, bq.w, acc[q][3]);
        }
      }
      __syncthreads();
    }
    // pd + insertion, ascending m within this thread
    #pragma unroll
    for (int q=0;q<8;q++){
      float4 xm = *reinterpret_cast<const float4*>(&xxb[mbase + q*32 + mc*4]);
      float xmv[4] = {xm.x, xm.y, xm.z, xm.w};
      #pragma unroll
      for (int e=0;e<4;e++){
        float t = 2.f*acc[q][e];
        float v = (t - xn) - xmv[e];
        if (v > vals[KK-1]){
          int m = mbase + q*32 + mc*4 + e;
          #pragma unroll
          for (int i=KK-1;i>0;--i){
            if (vals[i-1] < v){ vals[i]=vals[i-1]; inds[i]=inds[i-1]; }
          }
          bool done = false;
          #pragma unroll
          for (int i=0;i<KK;i++){
            bool pl = (!done) && (vals[i] < v);
            if (pl){ vals[i]=v; inds[i]=m; done=true; }
          }
        }
      }
    }
  }
  // 8-lane extraction: 20 rounds argmax (val desc, tie -> lower index)
  int* op = idx + ((size_t)b*NN + r0 + row)*KK;
  #pragma unroll 1
  for (int r = 0; r < KK; r++){
    float bv = vals[0]; int bi = inds[0];
    #pragma unroll
    for (int s = 1; s < 8; s <<= 1){
      float ov = __shfl_xor(bv, s);
      int   oi = __shfl_xor(bi, s);
      if (ov > bv || (ov == bv && oi < bi)){ bv = ov; bi = oi; }
    }
    if (inds[0] == bi){    // disjoint index classes: exactly one owner
      #pragma unroll
      for (int i=0;i<KK-1;i++){ vals[i]=vals[i+1]; inds[i]=inds[i+1]; }
      vals[KK-1] = -INFINITY; inds[KK-1] = NN;
    }
    if (mc == 0) op[r] = bi;
  }
}

// u[(b*N+n)*O+o] = sum_c wtf[c][o]*x; v with wtd
// (all batches, f64 accumulate — REQUIRED: u/v feed next-layer KNN features;
//  f32 accumulation here flipped a KNN boundary in round 13. DO NOT TOUCH.)
__global__ __launch_bounds__(256) void k_gemm_uv(
    const float* __restrict__ x, int C, int O, size_t bs,
    const float* __restrict__ wtf, const float* __restrict__ wtd,
    float* __restrict__ u, float* __restrict__ v){
  __shared__ float Xs[8][TS];
  __shared__ float Wfs[8][TS];
  __shared__ float Wds[8][TS];
  int b = blockIdx.z;
  int n0 = blockIdx.y*TS, o0 = blockIdx.x*TS;
  int tid = threadIdx.x, tx = tid%16, ty = tid/16;
  const float* xb = x + (size_t)b*bs;
  double au[4][4] = {};
  double av[4][4] = {};
  for (int c0 = 0; c0 < C; c0 += 8){
    int r = tid/64, col = tid%64;
    #pragma unroll
    for (int rr=0;rr<2;rr++){
      int c = c0 + r + rr*4;
      float xv=0.f, wfv=0.f, wdv=0.f;
      if (c < C){
        xv = xb[(size_t)c*NN + n0 + col];
        if (o0+col < O){
          wfv = wtf[(size_t)c*O + o0+col];
          wdv = wtd[(size_t)c*O + o0+col];
        }
      }
      Xs[r+rr*4][col]=xv; Wfs[r+rr*4][col]=wfv; Wds[r+rr*4][col]=wdv;
    }
    __syncthreads();
    #pragma unroll
    for (int c=0;c<8;c++){
      double a[4], f[4], d[4];
      #pragma unroll
      for (int i=0;i<4;i++) a[i] = (double)Xs[c][ty*4+i];
      #pragma unroll
      for (int j=0;j<4;j++) f[j] = (double)Wfs[c][tx*4+j];
      #pragma unroll
      for (int j=0;j<4;j++) d[j] = (double)Wds[c][tx*4+j];
      #pragma unroll
      for (int i=0;i<4;i++)
        #pragma unroll
        for (int j=0;j<4;j++){
          au[i][j] = fma(a[i], f[j], au[i][j]);
          av[i][j] = fma(a[i], d[j], av[i][j]);
        }
    }
    __syncthreads();
  }
  #pragma unroll
  for (int i=0;i<4;i++){
    int n = n0 + ty*4 + i;
    #pragma unroll
    for (int j=0;j<4;j++){
      int o = o0 + tx*4 + j;
      if (o < O){
        u[((size_t)b*NN + n)*O + o] = (float)au[i][j];
        v[((size_t)b*NN + n)*O + o] = (float)av[i][j];
      }
    }
  }
}

// gather: running max/min of y=u[idx]+v; f64 stats atomics (all batches)
#define NT 32
__global__ __launch_bounds__(256) void k_passB(
  const float* __restrict__ u, const float* __restrict__ v, const int* __restrict__ idx,
  int O, int OT, float* __restrict__ ymax, float* __restrict__ ymin,
  double* __restrict__ s1, double* __restrict__ s2){
  __shared__ int ids[NT*KK];
  int b = blockIdx.y, n0 = blockIdx.x*NT;
  int tid = threadIdx.x;
  for (int t = tid; t < NT*KK; t += 256) ids[t] = idx[((size_t)b*NN + n0)*KK + t];
  __syncthreads();
  int nsplit = 256/OT;
  int ob = tid % OT, ns = tid / OT;
  int nper = NT / nsplit;
  const float* ub = u + (size_t)b*NN*O;
  const float* vb = v + (size_t)b*NN*O;
  for (int o = ob; o < O; o += 256){
    double s1p = 0.0, s2p = 0.0;
    for (int ni = ns*nper; ni < (ns+1)*nper; ni++){
      double su=0.0, sq=0.0;
      float mx=-INFINITY, mn=INFINITY;
      #pragma unroll
      for (int k=0;k<KK;k++){
        int j = ids[ni*KK + k];
        float uu = ub[(size_t)j*O + o];
        double ud = (double)uu;
        su += ud; sq += ud*ud;
        mx = fmaxf(mx, uu); mn = fminf(mn, uu);
      }
      float vv = vb[(size_t)(n0+ni)*O + o];
      double vd = (double)vv;
      s1p += su + (double)KK*vd;
      s2p += sq + 2.0*vd*su + (double)KK*vd*vd;
      size_t yo = ((size_t)b*NN + n0 + ni)*O + o;
      ymax[yo] = mx + vv; ymin[yo] = mn + vv;
    }
    atomicAdd(&s1[o], s1p);
    atomicAdd(&s2[o], s2p);
  }
}

// affine+lrelu (pick ymax/ymin by sign of scale), transpose -> (b,o,n).
// scale/shift computed in-block from s1/s2 (identical f64 expr as old stats_fin).
__global__ __launch_bounds__(256) void k_passD(const float* __restrict__ ymax,
  const float* __restrict__ ymin, const double* __restrict__ s1,
  const double* __restrict__ s2, const float* __restrict__ g,
  const float* __restrict__ bb, int O, double M, float* __restrict__ xout){
  __shared__ float t[64][65];
  __shared__ double s_sc[64], s_sh[64];
  int b = blockIdx.z, n0 = blockIdx.y*64, o0 = blockIdx.x*64;
  int tid = threadIdx.x;
  if (tid < 64){
    int o = o0 + tid;
    double sc = 0.0, sh = 0.0;
    if (o < O){
      double mean = s1[o]/M;
      double var  = s2[o]/M - mean*mean;
      sc = (double)g[o] / sqrt(var + EPSD);
      sh = (double)bb[o] - mean*sc;
    }
    s_sc[tid] = sc; s_sh[tid] = sh;
  }
  __syncthreads();
  int col = tid % 64, rr = tid / 64;
  int o = o0 + col;
  bool ov = (o < O);
  double sc = s_sc[col];
  double sh = s_sh[col];
  const float* src = (sc >= 0.0) ? ymax : ymin;
  for (int p = 0; p < 16; p++){
    int n = n0 + p*4 + rr;
    float y = ov ? src[((size_t)b*NN + n)*O + o] : 0.f;
    double z = sc*(double)y + sh;
    z = z > 0.0 ? z : SLOPED*z;
    t[p*4+rr][col] = (float)z;
  }
  __syncthreads();
  float* xb = xout + (size_t)b*OCN;
  for (int p = 0; p < 16; p++){
    int row = p*4 + rr;
    if (o0 + row < O) xb[(size_t)(o0+row)*NN + n0 + col] = t[col][row];
  }
}

// layer-5 conv as tiled f32 GEMM; c-chunk 8 (r14-proven: 8KB LDS, ~22% occ).
// c-chunk 16 regressed (r15: 16KB LDS halved occupancy, 339->547us). KEEP 8.
__global__ __launch_bounds__(256) void k_conv5g(const float* __restrict__ xf,
                                                const float* __restrict__ w5t,
                                                float* __restrict__ y5){
  __shared__ float Wsh[8][128];
  __shared__ float Xs[8][128];
  int o0 = blockIdx.x*128, n0 = blockIdx.y*128, b = blockIdx.z;
  int tid = threadIdx.x;
  int ty = tid / 16, tx = tid % 16;
  const float* xb = xf + (size_t)b*OCN;
  float acc[8][8] = {};
  for (int c0 = 0; c0 < 513; c0 += 8){
    #pragma unroll
    for (int rr = 0; rr < 4; rr++){
      int t2 = tid + rr*256;
      int c = t2 >> 7, col = t2 & 127;
      int cc = c0 + c;
      float wv = 0.f, xv = 0.f;
      if (cc < 513){
        wv = w5t[(size_t)cc*1024 + o0 + col];
        xv = xb[(size_t)cc*NN + n0 + col];
      }
      Wsh[c][col] = wv; Xs[c][col] = xv;
    }
    __syncthreads();
    #pragma unroll
    for (int c = 0; c < 8; c++){
      float4 w0 = *reinterpret_cast<const float4*>(&Wsh[c][ty*8]);
      float4 w1 = *reinterpret_cast<const float4*>(&Wsh[c][ty*8+4]);
      float4 x0 = *reinterpret_cast<const float4*>(&Xs[c][tx*4]);
      float4 x1 = *reinterpret_cast<const float4*>(&Xs[c][64 + tx*4]);
      float wr[8] = {w0.x,w0.y,w0.z,w0.w,w1.x,w1.y,w1.z,w1.w};
      float xr[8] = {x0.x,x0.y,x0.z,x0.w,x1.x,x1.y,x1.z,x1.w};
      #pragma unroll
      for (int i=0;i<8;i++)
        #pragma unroll
        for (int j=0;j<8;j++)
          acc[i][j] = fmaf(wr[i], xr[j], acc[i][j]);
    }
    __syncthreads();
  }
  #pragma unroll
  for (int i=0;i<8;i++){
    int o = o0 + ty*8 + i;
    float* yr = y5 + ((size_t)b*1024 + o)*NN;
    float4 v0 = {acc[i][0], acc[i][1], acc[i][2], acc[i][3]};
    float4 v1 = {acc[i][4], acc[i][5], acc[i][6], acc[i][7]};
    *reinterpret_cast<float4*>(&yr[n0 + tx*4])      = v0;
    *reinterpret_cast<float4*>(&yr[n0 + 64 + tx*4]) = v1;
  }
}

__global__ __launch_bounds__(256) void k_stats5_v2(const float* __restrict__ y5,
                                                   const float* __restrict__ g,
                                                   const float* __restrict__ bb,
                                                   double* __restrict__ scale,
                                                   double* __restrict__ shift){
  int o = blockIdx.x;
  __shared__ double sh1[256], sh2[256];
  double a = 0.0, q = 0.0;
  for (int bn = threadIdx.x; bn < BB*NN; bn += 256){
    int b = bn >> 11, n = bn & 2047;
    double yv = (double)y5[((size_t)b*1024 + o)*NN + n];
    a += yv; q += yv*yv;
  }
  sh1[threadIdx.x] = a; sh2[threadIdx.x] = q;
  __syncthreads();
  for (int s = 128; s > 0; s >>= 1){
    if (threadIdx.x < s){ sh1[threadIdx.x] += sh1[threadIdx.x+s]; sh2[threadIdx.x] += sh2[threadIdx.x+s]; }
    __syncthreads();
  }
  if (threadIdx.x == 0){
    double M = (double)(BB*NN);
    double mean = sh1[0]/M;
    double var  = sh2[0]/M - mean*mean;
    double sc = (double)g[o]/sqrt(var + EPSD);
    scale[o] = sc;
    shift[o] = (double)bb[o] - mean*sc;
  }
}

__global__ __launch_bounds__(256) void k_final5_v2(const float* __restrict__ y5,
                                                   const double* __restrict__ scale,
                                                   const double* __restrict__ shift,
                                                   float* __restrict__ out){
  int o = blockIdx.x, b = blockIdx.y;
  __shared__ double smx[256], ssm[256];
  double sc = scale[o], sh = shift[o];
  double mx = -INFINITY, sm = 0.0;
  const float* yrow = y5 + ((size_t)b*1024 + o)*NN;
  for (int n = threadIdx.x; n < NN; n += 256){
    double z = sc*(double)yrow[n] + sh;
    z = z > 0.0 ? z : SLOPED*z;
    mx = fmax(mx, z); sm += z;
  }
  smx[threadIdx.x] = mx; ssm[threadIdx.x] = sm;
  __syncthreads();
  for (int s = 128; s > 0; s >>= 1){
    if (threadIdx.x < s){
      smx[threadIdx.x] = fmax(smx[threadIdx.x], smx[threadIdx.x+s]);
      ssm[threadIdx.x] += ssm[threadIdx.x+s];
    }
    __syncthreads();
  }
  float vg = (float)smx[0];
  float va = (float)(ssm[0]*(1.0/NN));
  float* ob = out + (size_t)b*OCN;
  for (int n = threadIdx.x; n < NN; n += 256){
    ob[(size_t)o*NN + n] = vg;
    ob[(size_t)(1024+o)*NN + n] = va;
  }
}

extern "C" void kernel_launch(void* const* d_in, const int* in_sizes, int n_in,
                              void* d_out, int out_size, void* d_ws, size_t ws_size,
                              hipStream_t stream){
  const float* xyz = (const float*)d_in[0];
  float* out = (float*)d_out;
  float* ws  = (float*)d_ws;

  const float* Wp[5] = {(const float*)d_in[1],(const float*)d_in[4],(const float*)d_in[7],(const float*)d_in[10],(const float*)d_in[13]};
  const float* Gp[5] = {(const float*)d_in[2],(const float*)d_in[5],(const float*)d_in[8],(const float*)d_in[11],(const float*)d_in[14]};
  const float* Bp[5] = {(const float*)d_in[3],(const float*)d_in[6],(const float*)d_in[9],(const float*)d_in[12],(const float*)d_in[15]};
  int Cin[4]  = {3, 64, 64, 128};
  int Oc[4]   = {64, 64, 128, 257};
  int xinc[4] = {2048, 2051, 2115, 2179};
  int xoutc[4]= {2051, 2115, 2179, 2307};
  int woff[4] = {0, 192, 4288, 12480};

  float* ymx  = ws + WS_YMX;
  float* ymn  = ws + WS_YMN;
  float* u    = ws + WS_U;
  float* v    = ws + WS_V;
  int*   idx  = (int*)(ws + WS_IDX);
  float* xx   = ws + WS_XX;
  float* wtf  = ws + WS_WTF;
  float* wtd  = ws + WS_WTD;
  float* w5t  = ws + WS_W5T;
  float* y5   = ws + WS_Y5;
  double* s1d = (double*)(ws + WS_S1);
  double* s2d = (double*)(ws + WS_S2);
  double* scd = (double*)(ws + WS_SC);
  double* shd = (double*)(ws + WS_SH);

  k_prep_x0<<<cdiv(BB*NN,256), 256, 0, stream>>>(xyz, out);
  k_wt_all <<<cdiv(513*1024,256), 256, 0, stream>>>(Wp[0], Wp[1], Wp[2], Wp[3], Wp[4], wtf, wtd, w5t);

  for (int t = 0; t < 4; t++){
    int C = Cin[t], O = Oc[t];
    const float* xin = out + (size_t)xinc[t]*NN;
    k_xx32<<<dim3(NN/256, BB), 256, 0, stream>>>(xin, C, OCN, xx, s1d, s2d);
    int OT = (O <= 64) ? 64 : ((O <= 128) ? 128 : 256);
    k_pdtopk<<<dim3(NN/32, BB), 256, 0, stream>>>(xin, C, OCN, xx, idx);
    k_gemm_uv<<<dim3(cdiv(O,TS), NN/TS, BB), 256, 0, stream>>>(xin, C, O, OCN, wtf + woff[t], wtd + woff[t], u, v);
    k_passB  <<<dim3(NN/NT, BB), 256, 0, stream>>>(u, v, idx, O, OT, ymx, ymn, s1d, s2d);
    k_passD  <<<dim3(cdiv(O,TS), NN/TS, BB), 256, 0, stream>>>(ymx, ymn, s1d, s2d, Gp[t], Bp[t], O,
               (double)((size_t)BB*NN*KK), out + (size_t)xoutc[t]*NN);
  }

  // ---- layer 5 (1x1 conv 513 -> 1024) + global pooling ----
  k_conv5g<<<dim3(1024/128, NN/128, BB), 256, 0, stream>>>(out + (size_t)2051*NN, w5t, y5);
  k_stats5_v2<<<1024, 256, 0, stream>>>(y5, Gp[4], Bp[4], scd, shd);
  k_final5_v2<<<dim3(1024, BB), 256, 0, stream>>>(y5, scd, shd, out);
}

// Round 19
// 2422.784 us; speedup vs baseline: 1.1996x; 1.1996x over previous
//
#include <hip/hip_runtime.h>
#include <math.h>

#define BB 8
#define NN 2048
#define KK 20
#define OCH 2564
#define OCN ((size_t)OCH*NN)
#define EPSD 1e-5
#define SLOPED 0.2
#define TS 64

// ---------------- ws layout (float offsets) — ALL DISJOINT while alive ----
// During KNN phase (pd/topk), ymx/ymn/u are dead => used as extra pd buffers.
// y5 (B*1024*N = 16,777,216 f32) overlays PD/YMX/YMN/U at layer 5 (all dead).
#define WS_PD   ((size_t)0)
#define WS_YMX  ((size_t)4194304)
#define WS_YMN  ((size_t)8404992)
#define WS_U    ((size_t)12615680)
#define WS_V    ((size_t)16826368)
#define WS_IDX  ((size_t)21037056)
#define WS_XX   ((size_t)21364736)
#define WS_WTF  ((size_t)21381120)   // 45376 floats, per-layer offsets {0,192,4288,12480}
#define WS_WTD  ((size_t)21426496)   // 45376
#define WS_W5T  ((size_t)21471872)   // 525312
#define WS_Y5   ((size_t)0)
#define WS_S1   ((size_t)21997184)   // 1024 doubles
#define WS_S2   (WS_S1 + 2048)
#define WS_SC   (WS_S2 + 2048)       // 1024 doubles (layer-5 scale)
#define WS_SH   (WS_SC + 2048)

static inline int cdiv(int a, int b){ return (a+b-1)/b; }

// out[b, 2048+c, n] = xyz[b,n,c]  (features live in `out`; no separate copies)
__global__ void k_prep_x0(const float* __restrict__ xyz, float* __restrict__ out){
  int id = blockIdx.x*256 + threadIdx.x;
  if (id >= BB*NN) return;
  int b = id / NN, n = id % NN;
  const float* p = xyz + ((size_t)b*NN + n)*3;
  float* o = out + (size_t)b*OCN + (size_t)2048*NN + n;
  o[0] = p[0]; o[(size_t)NN] = p[1]; o[2*(size_t)NN] = p[2];
}

// one-shot weight transpose for all 5 layers
__global__ void k_wt_all(const float* __restrict__ W1, const float* __restrict__ W2,
                         const float* __restrict__ W3, const float* __restrict__ W4,
                         const float* __restrict__ W5,
                         float* __restrict__ wtf, float* __restrict__ wtd,
                         float* __restrict__ w5t){
  int id = blockIdx.x*256 + threadIdx.x;
  if (id < 513*1024){
    int c = id / 1024, o = id % 1024;
    w5t[(size_t)c*1024 + o] = W5[(size_t)o*513 + c];
  }
  if (id < 45376){
    const float* W; int C, O; int base;
    if (id < 192)        { W = W1; C = 3;   O = 64;  base = 0; }
    else if (id < 4288)  { W = W2; C = 64;  O = 64;  base = 192; }
    else if (id < 12480) { W = W3; C = 64;  O = 128; base = 4288; }
    else                 { W = W4; C = 128; O = 257; base = 12480; }
    int r = id - base;
    int c = r / O, o = r % O;
    float wf = W[(size_t)o*(2*C) + c];
    float wc = W[(size_t)o*(2*C) + C + c];
    wtf[base + (size_t)c*O + o] = wf;
    wtd[base + (size_t)c*O + o] = wc - wf;
  }
}

// ---- KNN arithmetic: per-output chains validated round 8 (canonical f32) ----
// block (0,0) zeroes s1/s2 for this layer
__global__ void k_xx32(const float* __restrict__ x, int C, size_t bs, float* __restrict__ xx,
                       double* __restrict__ s1, double* __restrict__ s2){
  if (blockIdx.x == 0 && blockIdx.y == 0){
    int t = threadIdx.x;
    #pragma unroll
    for (int i=0;i<4;i++){ s1[t*4+i] = 0.0; s2[t*4+i] = 0.0; }
  }
  int b = blockIdx.y;
  int n = blockIdx.x*256 + threadIdx.x;
  const float* p = x + (size_t)b*bs + n;
  float a;
  if (C <= 8){
    a = 0.f;
    for (int c = 0; c < C; c++){ float v = p[(size_t)c*NN]; float s = v*v; a = a + s; }
  } else {
    float r0,r1,r2,r3,r4,r5,r6,r7;
    { float v;
      v = p[0];            r0 = v*v;
      v = p[(size_t)1*NN]; r1 = v*v;
      v = p[(size_t)2*NN]; r2 = v*v;
      v = p[(size_t)3*NN]; r3 = v*v;
      v = p[(size_t)4*NN]; r4 = v*v;
      v = p[(size_t)5*NN]; r5 = v*v;
      v = p[(size_t)6*NN]; r6 = v*v;
      v = p[(size_t)7*NN]; r7 = v*v;
    }
    for (int i = 8; i < C; i += 8){
      float v;
      v = p[(size_t)(i+0)*NN]; r0 = r0 + v*v;
      v = p[(size_t)(i+1)*NN]; r1 = r1 + v*v;
      v = p[(size_t)(i+2)*NN]; r2 = r2 + v*v;
      v = p[(size_t)(i+3)*NN]; r3 = r3 + v*v;
      v = p[(size_t)(i+4)*NN]; r4 = r4 + v*v;
      v = p[(size_t)(i+5)*NN]; r5 = r5 + v*v;
      v = p[(size_t)(i+6)*NN]; r6 = r6 + v*v;
      v = p[(size_t)(i+7)*NN]; r7 = r7 + v*v;
    }
    a = ((r0+r1)+(r2+r3)) + ((r4+r5)+(r6+r7));
  }
  xx[b*NN + n] = a;
}

// 128x128 tile, 4 batches via blockIdx.z -> 4 disjoint pd buffers.
// Per-output fmaf chain identical to validated version (bit-exact).
// NOTE r18: fusing pd+topk (no pd materialization) REGRESSED 655us/layer —
// pd round-trip is L2/L3-resident and ~free; keep the separate pipeline.
__global__ __launch_bounds__(256) void k_pd4(const float* __restrict__ x, int C, size_t bs, int b0,
                     const float* __restrict__ xx, float* __restrict__ wsbase,
                     unsigned long long o0, unsigned long long o1,
                     unsigned long long o2, unsigned long long o3){
  int z = blockIdx.z;
  unsigned long long off = (z==0)?o0:((z==1)?o1:((z==2)?o2:o3));
  float* pd = wsbase + off;
  int b = b0 + z;
  __shared__ float As[8][128];
  __shared__ float Bs[8][128];
  int n0 = blockIdx.y*128, m0 = blockIdx.x*128;
  int tid = threadIdx.x;
  int ty = tid / 16, tx = tid % 16;
  const float* xb = x + (size_t)b*bs;
  float acc[8][8] = {};
  for (int c0 = 0; c0 < C; c0 += 8){
    #pragma unroll
    for (int rr = 0; rr < 4; rr++){
      int t2 = tid + rr*256;
      int c = t2 >> 7, col = t2 & 127;
      int cc = c0 + c;
      float av = 0.f, bv = 0.f;
      if (cc < C){ av = xb[(size_t)cc*NN + n0 + col]; bv = xb[(size_t)cc*NN + m0 + col]; }
      As[c][col] = av; Bs[c][col] = bv;
    }
    __syncthreads();
    #pragma unroll
    for (int c = 0; c < 8; c++){
      float4 a0 = *reinterpret_cast<const float4*>(&As[c][ty*8]);
      float4 a1 = *reinterpret_cast<const float4*>(&As[c][ty*8+4]);
      float4 b0v = *reinterpret_cast<const float4*>(&Bs[c][tx*4]);
      float4 b1v = *reinterpret_cast<const float4*>(&Bs[c][64 + tx*4]);
      float a[8]  = {a0.x,a0.y,a0.z,a0.w,a1.x,a1.y,a1.z,a1.w};
      float bv[8] = {b0v.x,b0v.y,b0v.z,b0v.w,b1v.x,b1v.y,b1v.z,b1v.w};
      #pragma unroll
      for (int i=0;i<8;i++)
        #pragma unroll
        for (int j=0;j<8;j++)
          acc[i][j] = fmaf(a[i], bv[j], acc[i][j]);
    }
    __syncthreads();
  }
  const float* xxb = xx + b*NN;
  float xm0[4], xm1[4];
  #pragma unroll
  for (int j=0;j<4;j++){ xm0[j] = xxb[m0 + tx*4 + j]; xm1[j] = xxb[m0 + 64 + tx*4 + j]; }
  #pragma unroll
  for (int i=0;i<8;i++){
    int n = n0 + ty*8 + i;
    float xn = xxb[n];
    float4 v0, v1;
    v0.x = (2.f*acc[i][0] - xn) - xm0[0];
    v0.y = (2.f*acc[i][1] - xn) - xm0[1];
    v0.z = (2.f*acc[i][2] - xn) - xm0[2];
    v0.w = (2.f*acc[i][3] - xn) - xm0[3];
    v1.x = (2.f*acc[i][4] - xn) - xm1[0];
    v1.y = (2.f*acc[i][5] - xn) - xm1[1];
    v1.z = (2.f*acc[i][6] - xn) - xm1[2];
    v1.w = (2.f*acc[i][7] - xn) - xm1[3];
    *reinterpret_cast<float4*>(&pd[(size_t)n*NN + m0 + tx*4])      = v0;
    *reinterpret_cast<float4*>(&pd[(size_t)n*NN + m0 + 64 + tx*4]) = v1;
  }
}

// deterministic top-20, 4 batches via blockIdx.y; set ≡ validated scans.
__global__ __launch_bounds__(256) void k_topk4(const float* __restrict__ wsbase,
                     unsigned long long o0, unsigned long long o1,
                     unsigned long long o2, unsigned long long o3,
                     int b0, int* __restrict__ idx){
  int z = blockIdx.y;
  unsigned long long off = (z==0)?o0:((z==1)?o1:((z==2)?o2:o3));
  const float* pdb = wsbase + off;
  int b = b0 + z;
  int lane = threadIdx.x & 63;
  int w = threadIdx.x >> 6;
  int n = blockIdx.x*4 + w;
  const float* row = pdb + (size_t)n*NN;
  float vals[KK]; int inds[KK];
  #pragma unroll
  for (int i=0;i<KK;i++){ vals[i] = -INFINITY; inds[i] = NN; }
  for (int c = 0; c < NN/64; c++){
    int m = c*64 + lane;
    float v = row[m];
    if (v > vals[KK-1]){
      #pragma unroll
      for (int i=KK-1;i>0;--i){
        if (vals[i-1] < v){ vals[i]=vals[i-1]; inds[i]=inds[i-1]; }
      }
      bool done = false;
      #pragma unroll
      for (int i=0;i<KK;i++){
        bool pl = (!done) && (vals[i] < v);
        if (pl){ vals[i]=v; inds[i]=m; done=true; }
      }
    }
  }
  int* op = idx + ((size_t)b*NN + n)*KK;
  #pragma unroll 1
  for (int r = 0; r < KK; r++){
    float bv = vals[0]; int bi = inds[0];
    #pragma unroll
    for (int s = 1; s < 64; s <<= 1){
      float ov = __shfl_xor(bv, s);
      int   oi = __shfl_xor(bi, s);
      if (ov > bv || (ov == bv && oi < bi)){ bv = ov; bi = oi; }
    }
    if (inds[0] == bi){
      #pragma unroll
      for (int i=0;i<KK-1;i++){ vals[i]=vals[i+1]; inds[i]=inds[i+1]; }
      vals[KK-1] = -INFINITY; inds[KK-1] = NN;
    }
    if (lane == 0) op[r] = bi;
  }
}

// u[(b*N+n)*O+o] = sum_c wtf[c][o]*x; v with wtd
// (all batches, f64 accumulate — REQUIRED: u/v feed next-layer KNN features;
//  f32 accumulation here flipped a KNN boundary in round 13. DO NOT TOUCH.)
__global__ __launch_bounds__(256) void k_gemm_uv(
    const float* __restrict__ x, int C, int O, size_t bs,
    const float* __restrict__ wtf, const float* __restrict__ wtd,
    float* __restrict__ u, float* __restrict__ v){
  __shared__ float Xs[8][TS];
  __shared__ float Wfs[8][TS];
  __shared__ float Wds[8][TS];
  int b = blockIdx.z;
  int n0 = blockIdx.y*TS, o0 = blockIdx.x*TS;
  int tid = threadIdx.x, tx = tid%16, ty = tid/16;
  const float* xb = x + (size_t)b*bs;
  double au[4][4] = {};
  double av[4][4] = {};
  for (int c0 = 0; c0 < C; c0 += 8){
    int r = tid/64, col = tid%64;
    #pragma unroll
    for (int rr=0;rr<2;rr++){
      int c = c0 + r + rr*4;
      float xv=0.f, wfv=0.f, wdv=0.f;
      if (c < C){
        xv = xb[(size_t)c*NN + n0 + col];
        if (o0+col < O){
          wfv = wtf[(size_t)c*O + o0+col];
          wdv = wtd[(size_t)c*O + o0+col];
        }
      }
      Xs[r+rr*4][col]=xv; Wfs[r+rr*4][col]=wfv; Wds[r+rr*4][col]=wdv;
    }
    __syncthreads();
    #pragma unroll
    for (int c=0;c<8;c++){
      double a[4], f[4], d[4];
      #pragma unroll
      for (int i=0;i<4;i++) a[i] = (double)Xs[c][ty*4+i];
      #pragma unroll
      for (int j=0;j<4;j++) f[j] = (double)Wfs[c][tx*4+j];
      #pragma unroll
      for (int j=0;j<4;j++) d[j] = (double)Wds[c][tx*4+j];
      #pragma unroll
      for (int i=0;i<4;i++)
        #pragma unroll
        for (int j=0;j<4;j++){
          au[i][j] = fma(a[i], f[j], au[i][j]);
          av[i][j] = fma(a[i], d[j], av[i][j]);
        }
    }
    __syncthreads();
  }
  #pragma unroll
  for (int i=0;i<4;i++){
    int n = n0 + ty*4 + i;
    #pragma unroll
    for (int j=0;j<4;j++){
      int o = o0 + tx*4 + j;
      if (o < O){
        u[((size_t)b*NN + n)*O + o] = (float)au[i][j];
        v[((size_t)b*NN + n)*O + o] = (float)av[i][j];
      }
    }
  }
}

// gather: running max/min of y=u[idx]+v; f64 stats atomics (all batches)
#define NT 32
__global__ __launch_bounds__(256) void k_passB(
  const float* __restrict__ u, const float* __restrict__ v, const int* __restrict__ idx,
  int O, int OT, float* __restrict__ ymax, float* __restrict__ ymin,
  double* __restrict__ s1, double* __restrict__ s2){
  __shared__ int ids[NT*KK];
  int b = blockIdx.y, n0 = blockIdx.x*NT;
  int tid = threadIdx.x;
  for (int t = tid; t < NT*KK; t += 256) ids[t] = idx[((size_t)b*NN + n0)*KK + t];
  __syncthreads();
  int nsplit = 256/OT;
  int ob = tid % OT, ns = tid / OT;
  int nper = NT / nsplit;
  const float* ub = u + (size_t)b*NN*O;
  const float* vb = v + (size_t)b*NN*O;
  for (int o = ob; o < O; o += 256){
    double s1p = 0.0, s2p = 0.0;
    for (int ni = ns*nper; ni < (ns+1)*nper; ni++){
      double su=0.0, sq=0.0;
      float mx=-INFINITY, mn=INFINITY;
      #pragma unroll
      for (int k=0;k<KK;k++){
        int j = ids[ni*KK + k];
        float uu = ub[(size_t)j*O + o];
        double ud = (double)uu;
        su += ud; sq += ud*ud;
        mx = fmaxf(mx, uu); mn = fminf(mn, uu);
      }
      float vv = vb[(size_t)(n0+ni)*O + o];
      double vd = (double)vv;
      s1p += su + (double)KK*vd;
      s2p += sq + 2.0*vd*su + (double)KK*vd*vd;
      size_t yo = ((size_t)b*NN + n0 + ni)*O + o;
      ymax[yo] = mx + vv; ymin[yo] = mn + vv;
    }
    atomicAdd(&s1[o], s1p);
    atomicAdd(&s2[o], s2p);
  }
}

// affine+lrelu (pick ymax/ymin by sign of scale), transpose -> (b,o,n).
// scale/shift computed in-block from s1/s2 (identical f64 expr as old stats_fin).
__global__ __launch_bounds__(256) void k_passD(const float* __restrict__ ymax,
  const float* __restrict__ ymin, const double* __restrict__ s1,
  const double* __restrict__ s2, const float* __restrict__ g,
  const float* __restrict__ bb, int O, double M, float* __restrict__ xout){
  __shared__ float t[64][65];
  __shared__ double s_sc[64], s_sh[64];
  int b = blockIdx.z, n0 = blockIdx.y*64, o0 = blockIdx.x*64;
  int tid = threadIdx.x;
  if (tid < 64){
    int o = o0 + tid;
    double sc = 0.0, sh = 0.0;
    if (o < O){
      double mean = s1[o]/M;
      double var  = s2[o]/M - mean*mean;
      sc = (double)g[o] / sqrt(var + EPSD);
      sh = (double)bb[o] - mean*sc;
    }
    s_sc[tid] = sc; s_sh[tid] = sh;
  }
  __syncthreads();
  int col = tid % 64, rr = tid / 64;
  int o = o0 + col;
  bool ov = (o < O);
  double sc = s_sc[col];
  double sh = s_sh[col];
  const float* src = (sc >= 0.0) ? ymax : ymin;
  for (int p = 0; p < 16; p++){
    int n = n0 + p*4 + rr;
    float y = ov ? src[((size_t)b*NN + n)*O + o] : 0.f;
    double z = sc*(double)y + sh;
    z = z > 0.0 ? z : SLOPED*z;
    t[p*4+rr][col] = (float)z;
  }
  __syncthreads();
  float* xb = xout + (size_t)b*OCN;
  for (int p = 0; p < 16; p++){
    int row = p*4 + rr;
    if (o0 + row < O) xb[(size_t)(o0+row)*NN + n0 + col] = t[col][row];
  }
}

// layer-5 conv as tiled f32 GEMM; c-chunk 8 (r14-proven: 8KB LDS, ~22% occ).
// c-chunk 16 regressed (r15: 16KB LDS halved occupancy, 339->547us). KEEP 8.
__global__ __launch_bounds__(256) void k_conv5g(const float* __restrict__ xf,
                                                const float* __restrict__ w5t,
                                                float* __restrict__ y5){
  __shared__ float Wsh[8][128];
  __shared__ float Xs[8][128];
  int o0 = blockIdx.x*128, n0 = blockIdx.y*128, b = blockIdx.z;
  int tid = threadIdx.x;
  int ty = tid / 16, tx = tid % 16;
  const float* xb = xf + (size_t)b*OCN;
  float acc[8][8] = {};
  for (int c0 = 0; c0 < 513; c0 += 8){
    #pragma unroll
    for (int rr = 0; rr < 4; rr++){
      int t2 = tid + rr*256;
      int c = t2 >> 7, col = t2 & 127;
      int cc = c0 + c;
      float wv = 0.f, xv = 0.f;
      if (cc < 513){
        wv = w5t[(size_t)cc*1024 + o0 + col];
        xv = xb[(size_t)cc*NN + n0 + col];
      }
      Wsh[c][col] = wv; Xs[c][col] = xv;
    }
    __syncthreads();
    #pragma unroll
    for (int c = 0; c < 8; c++){
      float4 w0 = *reinterpret_cast<const float4*>(&Wsh[c][ty*8]);
      float4 w1 = *reinterpret_cast<const float4*>(&Wsh[c][ty*8+4]);
      float4 x0 = *reinterpret_cast<const float4*>(&Xs[c][tx*4]);
      float4 x1 = *reinterpret_cast<const float4*>(&Xs[c][64 + tx*4]);
      float wr[8] = {w0.x,w0.y,w0.z,w0.w,w1.x,w1.y,w1.z,w1.w};
      float xr[8] = {x0.x,x0.y,x0.z,x0.w,x1.x,x1.y,x1.z,x1.w};
      #pragma unroll
      for (int i=0;i<8;i++)
        #pragma unroll
        for (int j=0;j<8;j++)
          acc[i][j] = fmaf(wr[i], xr[j], acc[i][j]);
    }
    __syncthreads();
  }
  #pragma unroll
  for (int i=0;i<8;i++){
    int o = o0 + ty*8 + i;
    float* yr = y5 + ((size_t)b*1024 + o)*NN;
    float4 v0 = {acc[i][0], acc[i][1], acc[i][2], acc[i][3]};
    float4 v1 = {acc[i][4], acc[i][5], acc[i][6], acc[i][7]};
    *reinterpret_cast<float4*>(&yr[n0 + tx*4])      = v0;
    *reinterpret_cast<float4*>(&yr[n0 + 64 + tx*4]) = v1;
  }
}

__global__ __launch_bounds__(256) void k_stats5_v2(const float* __restrict__ y5,
                                                   const float* __restrict__ g,
                                                   const float* __restrict__ bb,
                                                   double* __restrict__ scale,
                                                   double* __restrict__ shift){
  int o = blockIdx.x;
  __shared__ double sh1[256], sh2[256];
  double a = 0.0, q = 0.0;
  for (int bn = threadIdx.x; bn < BB*NN; bn += 256){
    int b = bn >> 11, n = bn & 2047;
    double yv = (double)y5[((size_t)b*1024 + o)*NN + n];
    a += yv; q += yv*yv;
  }
  sh1[threadIdx.x] = a; sh2[threadIdx.x] = q;
  __syncthreads();
  for (int s = 128; s > 0; s >>= 1){
    if (threadIdx.x < s){ sh1[threadIdx.x] += sh1[threadIdx.x+s]; sh2[threadIdx.x] += sh2[threadIdx.x+s]; }
    __syncthreads();
  }
  if (threadIdx.x == 0){
    double M = (double)(BB*NN);
    double mean = sh1[0]/M;
    double var  = sh2[0]/M - mean*mean;
    double sc = (double)g[o]/sqrt(var + EPSD);
    scale[o] = sc;
    shift[o] = (double)bb[o] - mean*sc;
  }
}

__global__ __launch_bounds__(256) void k_final5_v2(const float* __restrict__ y5,
                                                   const double* __restrict__ scale,
                                                   const double* __restrict__ shift,
                                                   float* __restrict__ out){
  int o = blockIdx.x, b = blockIdx.y;
  __shared__ double smx[256], ssm[256];
  double sc = scale[o], sh = shift[o];
  double mx = -INFINITY, sm = 0.0;
  const float* yrow = y5 + ((size_t)b*1024 + o)*NN;
  for (int n = threadIdx.x; n < NN; n += 256){
    double z = sc*(double)yrow[n] + sh;
    z = z > 0.0 ? z : SLOPED*z;
    mx = fmax(mx, z); sm += z;
  }
  smx[threadIdx.x] = mx; ssm[threadIdx.x] = sm;
  __syncthreads();
  for (int s = 128; s > 0; s >>= 1){
    if (threadIdx.x < s){
      smx[threadIdx.x] = fmax(smx[threadIdx.x], smx[threadIdx.x+s]);
      ssm[threadIdx.x] += ssm[threadIdx.x+s];
    }
    __syncthreads();
  }
  float vg = (float)smx[0];
  float va = (float)(ssm[0]*(1.0/NN));
  float* ob = out + (size_t)b*OCN;
  for (int n = threadIdx.x; n < NN; n += 256){
    ob[(size_t)o*NN + n] = vg;
    ob[(size_t)(1024+o)*NN + n] = va;
  }
}

extern "C" void kernel_launch(void* const* d_in, const int* in_sizes, int n_in,
                              void* d_out, int out_size, void* d_ws, size_t ws_size,
                              hipStream_t stream){
  const float* xyz = (const float*)d_in[0];
  float* out = (float*)d_out;
  float* ws  = (float*)d_ws;

  const float* Wp[5] = {(const float*)d_in[1],(const float*)d_in[4],(const float*)d_in[7],(const float*)d_in[10],(const float*)d_in[13]};
  const float* Gp[5] = {(const float*)d_in[2],(const float*)d_in[5],(const float*)d_in[8],(const float*)d_in[11],(const float*)d_in[14]};
  const float* Bp[5] = {(const float*)d_in[3],(const float*)d_in[6],(const float*)d_in[9],(const float*)d_in[12],(const float*)d_in[15]};
  int Cin[4]  = {3, 64, 64, 128};
  int Oc[4]   = {64, 64, 128, 257};
  int xinc[4] = {2048, 2051, 2115, 2179};
  int xoutc[4]= {2051, 2115, 2179, 2307};
  int woff[4] = {0, 192, 4288, 12480};

  float* ymx  = ws + WS_YMX;
  float* ymn  = ws + WS_YMN;
  float* u    = ws + WS_U;
  float* v    = ws + WS_V;
  int*   idx  = (int*)(ws + WS_IDX);
  float* xx   = ws + WS_XX;
  float* wtf  = ws + WS_WTF;
  float* wtd  = ws + WS_WTD;
  float* w5t  = ws + WS_W5T;
  float* y5   = ws + WS_Y5;
  double* s1d = (double*)(ws + WS_S1);
  double* s2d = (double*)(ws + WS_S2);
  double* scd = (double*)(ws + WS_SC);
  double* shd = (double*)(ws + WS_SH);

  k_prep_x0<<<cdiv(BB*NN,256), 256, 0, stream>>>(xyz, out);
  k_wt_all <<<cdiv(513*1024,256), 256, 0, stream>>>(Wp[0], Wp[1], Wp[2], Wp[3], Wp[4], wtf, wtd, w5t);

  for (int t = 0; t < 4; t++){
    int C = Cin[t], O = Oc[t];
    const float* xin = out + (size_t)xinc[t]*NN;
    k_xx32<<<dim3(NN/256, BB), 256, 0, stream>>>(xin, C, OCN, xx, s1d, s2d);
    int OT = (O <= 64) ? 64 : ((O <= 128) ? 128 : 256);
    for (int bg = 0; bg < 2; bg++){
      k_pd4  <<<dim3(NN/128, NN/128, 4), 256, 0, stream>>>(xin, C, OCN, bg*4, xx, ws,
               (unsigned long long)WS_PD, (unsigned long long)WS_YMX,
               (unsigned long long)WS_YMN, (unsigned long long)WS_U);
      k_topk4<<<dim3(NN/4, 4), 256, 0, stream>>>(ws,
               (unsigned long long)WS_PD, (unsigned long long)WS_YMX,
               (unsigned long long)WS_YMN, (unsigned long long)WS_U,
               bg*4, idx);
    }
    k_gemm_uv<<<dim3(cdiv(O,TS), NN/TS, BB), 256, 0, stream>>>(xin, C, O, OCN, wtf + woff[t], wtd + woff[t], u, v);
    k_passB  <<<dim3(NN/NT, BB), 256, 0, stream>>>(u, v, idx, O, OT, ymx, ymn, s1d, s2d);
    k_passD  <<<dim3(cdiv(O,TS), NN/TS, BB), 256, 0, stream>>>(ymx, ymn, s1d, s2d, Gp[t], Bp[t], O,
               (double)((size_t)BB*NN*KK), out + (size_t)xoutc[t]*NN);
  }

  // ---- layer 5 (1x1 conv 513 -> 1024) + global pooling ----
  k_conv5g<<<dim3(1024/128, NN/128, BB), 256, 0, stream>>>(out + (size_t)2051*NN, w5t, y5);
  k_stats5_v2<<<1024, 256, 0, stream>>>(y5, Gp[4], Bp[4], scd, shd);
  k_final5_v2<<<dim3(1024, BB), 256, 0, stream>>>(y5, scd, shd, out);
}

// Round 20
// 2407.511 us; speedup vs baseline: 1.2072x; 1.0063x over previous
//
#include <hip/hip_runtime.h>
#include <math.h>

#define BB 8
#define NN 2048
#define KK 20
#define OCH 2564
#define OCN ((size_t)OCH*NN)
#define EPSD 1e-5
#define SLOPED 0.2
#define TS 64

// ---------------- ws layout (float offsets) — ALL DISJOINT while alive ----
// During KNN phase (pd/topk), ymx/ymn/u are dead => used as extra pd buffers.
// y5 (B*1024*N = 16,777,216 f32) overlays PD/YMX/YMN/U at layer 5 (all dead).
// WS_SC/WS_SH are repurposed as layer-5 f64 stat accumulators (zeroed in k_wt_all).
#define WS_PD   ((size_t)0)
#define WS_YMX  ((size_t)4194304)
#define WS_YMN  ((size_t)8404992)
#define WS_U    ((size_t)12615680)
#define WS_V    ((size_t)16826368)
#define WS_IDX  ((size_t)21037056)
#define WS_XX   ((size_t)21364736)
#define WS_WTF  ((size_t)21381120)   // 45376 floats, per-layer offsets {0,192,4288,12480}
#define WS_WTD  ((size_t)21426496)   // 45376
#define WS_W5T  ((size_t)21471872)   // 525312
#define WS_Y5   ((size_t)0)
#define WS_S1   ((size_t)21997184)   // 1024 doubles (layers 1-4)
#define WS_S2   (WS_S1 + 2048)
#define WS_SC   (WS_S2 + 2048)       // 1024 doubles: layer-5 s1 accumulator
#define WS_SH   (WS_SC + 2048)       // 1024 doubles: layer-5 s2 accumulator

static inline int cdiv(int a, int b){ return (a+b-1)/b; }

// out[b, 2048+c, n] = xyz[b,n,c]  (features live in `out`; no separate copies)
__global__ void k_prep_x0(const float* __restrict__ xyz, float* __restrict__ out){
  int id = blockIdx.x*256 + threadIdx.x;
  if (id >= BB*NN) return;
  int b = id / NN, n = id % NN;
  const float* p = xyz + ((size_t)b*NN + n)*3;
  float* o = out + (size_t)b*OCN + (size_t)2048*NN + n;
  o[0] = p[0]; o[(size_t)NN] = p[1]; o[2*(size_t)NN] = p[2];
}

// one-shot weight transpose for all 5 layers + zero layer-5 stat accumulators
__global__ void k_wt_all(const float* __restrict__ W1, const float* __restrict__ W2,
                         const float* __restrict__ W3, const float* __restrict__ W4,
                         const float* __restrict__ W5,
                         float* __restrict__ wtf, float* __restrict__ wtd,
                         float* __restrict__ w5t,
                         double* __restrict__ s1b, double* __restrict__ s2b){
  int id = blockIdx.x*256 + threadIdx.x;
  if (id < 1024){ s1b[id] = 0.0; s2b[id] = 0.0; }
  if (id < 513*1024){
    int c = id / 1024, o = id % 1024;
    w5t[(size_t)c*1024 + o] = W5[(size_t)o*513 + c];
  }
  if (id < 45376){
    const float* W; int C, O; int base;
    if (id < 192)        { W = W1; C = 3;   O = 64;  base = 0; }
    else if (id < 4288)  { W = W2; C = 64;  O = 64;  base = 192; }
    else if (id < 12480) { W = W3; C = 64;  O = 128; base = 4288; }
    else                 { W = W4; C = 128; O = 257; base = 12480; }
    int r = id - base;
    int c = r / O, o = r % O;
    float wf = W[(size_t)o*(2*C) + c];
    float wc = W[(size_t)o*(2*C) + C + c];
    wtf[base + (size_t)c*O + o] = wf;
    wtd[base + (size_t)c*O + o] = wc - wf;
  }
}

// ---- KNN arithmetic: per-output chains validated round 8 (canonical f32) ----
// block (0,0) zeroes s1/s2 for this layer
__global__ void k_xx32(const float* __restrict__ x, int C, size_t bs, float* __restrict__ xx,
                       double* __restrict__ s1, double* __restrict__ s2){
  if (blockIdx.x == 0 && blockIdx.y == 0){
    int t = threadIdx.x;
    #pragma unroll
    for (int i=0;i<4;i++){ s1[t*4+i] = 0.0; s2[t*4+i] = 0.0; }
  }
  int b = blockIdx.y;
  int n = blockIdx.x*256 + threadIdx.x;
  const float* p = x + (size_t)b*bs + n;
  float a;
  if (C <= 8){
    a = 0.f;
    for (int c = 0; c < C; c++){ float v = p[(size_t)c*NN]; float s = v*v; a = a + s; }
  } else {
    float r0,r1,r2,r3,r4,r5,r6,r7;
    { float v;
      v = p[0];            r0 = v*v;
      v = p[(size_t)1*NN]; r1 = v*v;
      v = p[(size_t)2*NN]; r2 = v*v;
      v = p[(size_t)3*NN]; r3 = v*v;
      v = p[(size_t)4*NN]; r4 = v*v;
      v = p[(size_t)5*NN]; r5 = v*v;
      v = p[(size_t)6*NN]; r6 = v*v;
      v = p[(size_t)7*NN]; r7 = v*v;
    }
    for (int i = 8; i < C; i += 8){
      float v;
      v = p[(size_t)(i+0)*NN]; r0 = r0 + v*v;
      v = p[(size_t)(i+1)*NN]; r1 = r1 + v*v;
      v = p[(size_t)(i+2)*NN]; r2 = r2 + v*v;
      v = p[(size_t)(i+3)*NN]; r3 = r3 + v*v;
      v = p[(size_t)(i+4)*NN]; r4 = r4 + v*v;
      v = p[(size_t)(i+5)*NN]; r5 = r5 + v*v;
      v = p[(size_t)(i+6)*NN]; r6 = r6 + v*v;
      v = p[(size_t)(i+7)*NN]; r7 = r7 + v*v;
    }
    a = ((r0+r1)+(r2+r3)) + ((r4+r5)+(r6+r7));
  }
  xx[b*NN + n] = a;
}

// 128x128 tile, 4 batches via blockIdx.z -> 4 disjoint pd buffers.
// Per-output fmaf chain identical to validated version (bit-exact).
// NOTE r18: fusing pd+topk (no pd materialization) REGRESSED 655us/layer —
// pd round-trip is L2/L3-resident and ~free; keep the separate pipeline.
__global__ __launch_bounds__(256) void k_pd4(const float* __restrict__ x, int C, size_t bs, int b0,
                     const float* __restrict__ xx, float* __restrict__ wsbase,
                     unsigned long long o0, unsigned long long o1,
                     unsigned long long o2, unsigned long long o3){
  int z = blockIdx.z;
  unsigned long long off = (z==0)?o0:((z==1)?o1:((z==2)?o2:o3));
  float* pd = wsbase + off;
  int b = b0 + z;
  __shared__ float As[8][128];
  __shared__ float Bs[8][128];
  int n0 = blockIdx.y*128, m0 = blockIdx.x*128;
  int tid = threadIdx.x;
  int ty = tid / 16, tx = tid % 16;
  const float* xb = x + (size_t)b*bs;
  float acc[8][8] = {};
  for (int c0 = 0; c0 < C; c0 += 8){
    #pragma unroll
    for (int rr = 0; rr < 4; rr++){
      int t2 = tid + rr*256;
      int c = t2 >> 7, col = t2 & 127;
      int cc = c0 + c;
      float av = 0.f, bv = 0.f;
      if (cc < C){ av = xb[(size_t)cc*NN + n0 + col]; bv = xb[(size_t)cc*NN + m0 + col]; }
      As[c][col] = av; Bs[c][col] = bv;
    }
    __syncthreads();
    #pragma unroll
    for (int c = 0; c < 8; c++){
      float4 a0 = *reinterpret_cast<const float4*>(&As[c][ty*8]);
      float4 a1 = *reinterpret_cast<const float4*>(&As[c][ty*8+4]);
      float4 b0v = *reinterpret_cast<const float4*>(&Bs[c][tx*4]);
      float4 b1v = *reinterpret_cast<const float4*>(&Bs[c][64 + tx*4]);
      float a[8]  = {a0.x,a0.y,a0.z,a0.w,a1.x,a1.y,a1.z,a1.w};
      float bv[8] = {b0v.x,b0v.y,b0v.z,b0v.w,b1v.x,b1v.y,b1v.z,b1v.w};
      #pragma unroll
      for (int i=0;i<8;i++)
        #pragma unroll
        for (int j=0;j<8;j++)
          acc[i][j] = fmaf(a[i], bv[j], acc[i][j]);
    }
    __syncthreads();
  }
  const float* xxb = xx + b*NN;
  float xm0[4], xm1[4];
  #pragma unroll
  for (int j=0;j<4;j++){ xm0[j] = xxb[m0 + tx*4 + j]; xm1[j] = xxb[m0 + 64 + tx*4 + j]; }
  #pragma unroll
  for (int i=0;i<8;i++){
    int n = n0 + ty*8 + i;
    float xn = xxb[n];
    float4 v0, v1;
    v0.x = (2.f*acc[i][0] - xn) - xm0[0];
    v0.y = (2.f*acc[i][1] - xn) - xm0[1];
    v0.z = (2.f*acc[i][2] - xn) - xm0[2];
    v0.w = (2.f*acc[i][3] - xn) - xm0[3];
    v1.x = (2.f*acc[i][4] - xn) - xm1[0];
    v1.y = (2.f*acc[i][5] - xn) - xm1[1];
    v1.z = (2.f*acc[i][6] - xn) - xm1[2];
    v1.w = (2.f*acc[i][7] - xn) - xm1[3];
    *reinterpret_cast<float4*>(&pd[(size_t)n*NN + m0 + tx*4])      = v0;
    *reinterpret_cast<float4*>(&pd[(size_t)n*NN + m0 + 64 + tx*4]) = v1;
  }
}

// deterministic top-20, 4 batches via blockIdx.y; set ≡ validated scans.
__global__ __launch_bounds__(256) void k_topk4(const float* __restrict__ wsbase,
                     unsigned long long o0, unsigned long long o1,
                     unsigned long long o2, unsigned long long o3,
                     int b0, int* __restrict__ idx){
  int z = blockIdx.y;
  unsigned long long off = (z==0)?o0:((z==1)?o1:((z==2)?o2:o3));
  const float* pdb = wsbase + off;
  int b = b0 + z;
  int lane = threadIdx.x & 63;
  int w = threadIdx.x >> 6;
  int n = blockIdx.x*4 + w;
  const float* row = pdb + (size_t)n*NN;
  float vals[KK]; int inds[KK];
  #pragma unroll
  for (int i=0;i<KK;i++){ vals[i] = -INFINITY; inds[i] = NN; }
  for (int c = 0; c < NN/64; c++){
    int m = c*64 + lane;
    float v = row[m];
    if (v > vals[KK-1]){
      #pragma unroll
      for (int i=KK-1;i>0;--i){
        if (vals[i-1] < v){ vals[i]=vals[i-1]; inds[i]=inds[i-1]; }
      }
      bool done = false;
      #pragma unroll
      for (int i=0;i<KK;i++){
        bool pl = (!done) && (vals[i] < v);
        if (pl){ vals[i]=v; inds[i]=m; done=true; }
      }
    }
  }
  int* op = idx + ((size_t)b*NN + n)*KK;
  #pragma unroll 1
  for (int r = 0; r < KK; r++){
    float bv = vals[0]; int bi = inds[0];
    #pragma unroll
    for (int s = 1; s < 64; s <<= 1){
      float ov = __shfl_xor(bv, s);
      int   oi = __shfl_xor(bi, s);
      if (ov > bv || (ov == bv && oi < bi)){ bv = ov; bi = oi; }
    }
    if (inds[0] == bi){
      #pragma unroll
      for (int i=0;i<KK-1;i++){ vals[i]=vals[i+1]; inds[i]=inds[i+1]; }
      vals[KK-1] = -INFINITY; inds[KK-1] = NN;
    }
    if (lane == 0) op[r] = bi;
  }
}

// u[(b*N+n)*O+o] = sum_c wtf[c][o]*x; v with wtd
// (all batches, f64 accumulate — REQUIRED: u/v feed next-layer KNN features;
//  f32 accumulation here flipped a KNN boundary in round 13. DO NOT TOUCH.)
__global__ __launch_bounds__(256) void k_gemm_uv(
    const float* __restrict__ x, int C, int O, size_t bs,
    const float* __restrict__ wtf, const float* __restrict__ wtd,
    float* __restrict__ u, float* __restrict__ v){
  __shared__ float Xs[8][TS];
  __shared__ float Wfs[8][TS];
  __shared__ float Wds[8][TS];
  int b = blockIdx.z;
  int n0 = blockIdx.y*TS, o0 = blockIdx.x*TS;
  int tid = threadIdx.x, tx = tid%16, ty = tid/16;
  const float* xb = x + (size_t)b*bs;
  double au[4][4] = {};
  double av[4][4] = {};
  for (int c0 = 0; c0 < C; c0 += 8){
    int r = tid/64, col = tid%64;
    #pragma unroll
    for (int rr=0;rr<2;rr++){
      int c = c0 + r + rr*4;
      float xv=0.f, wfv=0.f, wdv=0.f;
      if (c < C){
        xv = xb[(size_t)c*NN + n0 + col];
        if (o0+col < O){
          wfv = wtf[(size_t)c*O + o0+col];
          wdv = wtd[(size_t)c*O + o0+col];
        }
      }
      Xs[r+rr*4][col]=xv; Wfs[r+rr*4][col]=wfv; Wds[r+rr*4][col]=wdv;
    }
    __syncthreads();
    #pragma unroll
    for (int c=0;c<8;c++){
      double a[4], f[4], d[4];
      #pragma unroll
      for (int i=0;i<4;i++) a[i] = (double)Xs[c][ty*4+i];
      #pragma unroll
      for (int j=0;j<4;j++) f[j] = (double)Wfs[c][tx*4+j];
      #pragma unroll
      for (int j=0;j<4;j++) d[j] = (double)Wds[c][tx*4+j];
      #pragma unroll
      for (int i=0;i<4;i++)
        #pragma unroll
        for (int j=0;j<4;j++){
          au[i][j] = fma(a[i], f[j], au[i][j]);
          av[i][j] = fma(a[i], d[j], av[i][j]);
        }
    }
    __syncthreads();
  }
  #pragma unroll
  for (int i=0;i<4;i++){
    int n = n0 + ty*4 + i;
    #pragma unroll
    for (int j=0;j<4;j++){
      int o = o0 + tx*4 + j;
      if (o < O){
        u[((size_t)b*NN + n)*O + o] = (float)au[i][j];
        v[((size_t)b*NN + n)*O + o] = (float)av[i][j];
      }
    }
  }
}

// gather: running max/min of y=u[idx]+v; f64 stats atomics (all batches)
#define NT 32
__global__ __launch_bounds__(256) void k_passB(
  const float* __restrict__ u, const float* __restrict__ v, const int* __restrict__ idx,
  int O, int OT, float* __restrict__ ymax, float* __restrict__ ymin,
  double* __restrict__ s1, double* __restrict__ s2){
  __shared__ int ids[NT*KK];
  int b = blockIdx.y, n0 = blockIdx.x*NT;
  int tid = threadIdx.x;
  for (int t = tid; t < NT*KK; t += 256) ids[t] = idx[((size_t)b*NN + n0)*KK + t];
  __syncthreads();
  int nsplit = 256/OT;
  int ob = tid % OT, ns = tid / OT;
  int nper = NT / nsplit;
  const float* ub = u + (size_t)b*NN*O;
  const float* vb = v + (size_t)b*NN*O;
  for (int o = ob; o < O; o += 256){
    double s1p = 0.0, s2p = 0.0;
    for (int ni = ns*nper; ni < (ns+1)*nper; ni++){
      double su=0.0, sq=0.0;
      float mx=-INFINITY, mn=INFINITY;
      #pragma unroll
      for (int k=0;k<KK;k++){
        int j = ids[ni*KK + k];
        float uu = ub[(size_t)j*O + o];
        double ud = (double)uu;
        su += ud; sq += ud*ud;
        mx = fmaxf(mx, uu); mn = fminf(mn, uu);
      }
      float vv = vb[(size_t)(n0+ni)*O + o];
      double vd = (double)vv;
      s1p += su + (double)KK*vd;
      s2p += sq + 2.0*vd*su + (double)KK*vd*vd;
      size_t yo = ((size_t)b*NN + n0 + ni)*O + o;
      ymax[yo] = mx + vv; ymin[yo] = mn + vv;
    }
    atomicAdd(&s1[o], s1p);
    atomicAdd(&s2[o], s2p);
  }
}

// affine+lrelu (pick ymax/ymin by sign of scale), transpose -> (b,o,n).
// scale/shift computed in-block from s1/s2 (identical f64 expr as old stats_fin).
__global__ __launch_bounds__(256) void k_passD(const float* __restrict__ ymax,
  const float* __restrict__ ymin, const double* __restrict__ s1,
  const double* __restrict__ s2, const float* __restrict__ g,
  const float* __restrict__ bb, int O, double M, float* __restrict__ xout){
  __shared__ float t[64][65];
  __shared__ double s_sc[64], s_sh[64];
  int b = blockIdx.z, n0 = blockIdx.y*64, o0 = blockIdx.x*64;
  int tid = threadIdx.x;
  if (tid < 64){
    int o = o0 + tid;
    double sc = 0.0, sh = 0.0;
    if (o < O){
      double mean = s1[o]/M;
      double var  = s2[o]/M - mean*mean;
      sc = (double)g[o] / sqrt(var + EPSD);
      sh = (double)bb[o] - mean*sc;
    }
    s_sc[tid] = sc; s_sh[tid] = sh;
  }
  __syncthreads();
  int col = tid % 64, rr = tid / 64;
  int o = o0 + col;
  bool ov = (o < O);
  double sc = s_sc[col];
  double sh = s_sh[col];
  const float* src = (sc >= 0.0) ? ymax : ymin;
  for (int p = 0; p < 16; p++){
    int n = n0 + p*4 + rr;
    float y = ov ? src[((size_t)b*NN + n)*O + o] : 0.f;
    double z = sc*(double)y + sh;
    z = z > 0.0 ? z : SLOPED*z;
    t[p*4+rr][col] = (float)z;
  }
  __syncthreads();
  float* xb = xout + (size_t)b*OCN;
  for (int p = 0; p < 16; p++){
    int row = p*4 + rr;
    if (o0 + row < O) xb[(size_t)(o0+row)*NN + n0 + col] = t[col][row];
  }
}

// layer-5 conv as tiled f32 GEMM; c-chunk 8 (r14-proven: 8KB LDS, ~22% occ).
// c-chunk 16 regressed (r15). KEEP 8.  Now fused with BN-stat partials:
// per-block f64 tile sums -> 16-lane shfl reduce -> 2 atomics/channel/block.
__global__ __launch_bounds__(256) void k_conv5g(const float* __restrict__ xf,
                                                const float* __restrict__ w5t,
                                                float* __restrict__ y5,
                                                double* __restrict__ s1b,
                                                double* __restrict__ s2b){
  __shared__ float Wsh[8][128];
  __shared__ float Xs[8][128];
  int o0 = blockIdx.x*128, n0 = blockIdx.y*128, b = blockIdx.z;
  int tid = threadIdx.x;
  int ty = tid / 16, tx = tid % 16;
  const float* xb = xf + (size_t)b*OCN;
  float acc[8][8] = {};
  for (int c0 = 0; c0 < 513; c0 += 8){
    #pragma unroll
    for (int rr = 0; rr < 4; rr++){
      int t2 = tid + rr*256;
      int c = t2 >> 7, col = t2 & 127;
      int cc = c0 + c;
      float wv = 0.f, xv = 0.f;
      if (cc < 513){
        wv = w5t[(size_t)cc*1024 + o0 + col];
        xv = xb[(size_t)cc*NN + n0 + col];
      }
      Wsh[c][col] = wv; Xs[c][col] = xv;
    }
    __syncthreads();
    #pragma unroll
    for (int c = 0; c < 8; c++){
      float4 w0 = *reinterpret_cast<const float4*>(&Wsh[c][ty*8]);
      float4 w1 = *reinterpret_cast<const float4*>(&Wsh[c][ty*8+4]);
      float4 x0 = *reinterpret_cast<const float4*>(&Xs[c][tx*4]);
      float4 x1 = *reinterpret_cast<const float4*>(&Xs[c][64 + tx*4]);
      float wr[8] = {w0.x,w0.y,w0.z,w0.w,w1.x,w1.y,w1.z,w1.w};
      float xr[8] = {x0.x,x0.y,x0.z,x0.w,x1.x,x1.y,x1.z,x1.w};
      #pragma unroll
      for (int i=0;i<8;i++)
        #pragma unroll
        for (int j=0;j<8;j++)
          acc[i][j] = fmaf(wr[i], xr[j], acc[i][j]);
    }
    __syncthreads();
  }
  #pragma unroll
  for (int i=0;i<8;i++){
    int o = o0 + ty*8 + i;
    float* yr = y5 + ((size_t)b*1024 + o)*NN;
    float4 v0 = {acc[i][0], acc[i][1], acc[i][2], acc[i][3]};
    float4 v1 = {acc[i][4], acc[i][5], acc[i][6], acc[i][7]};
    *reinterpret_cast<float4*>(&yr[n0 + tx*4])      = v0;
    *reinterpret_cast<float4*>(&yr[n0 + 64 + tx*4]) = v1;
  }
  // fused BN-stat partials: reduce this block's 128-n slice per channel.
  // ty occupies lanes [16*(ty%4), +16) within its wave, so xor s<16 reduces tx-groups.
  #pragma unroll
  for (int i=0;i<8;i++){
    double sy = 0.0, sq = 0.0;
    #pragma unroll
    for (int j=0;j<8;j++){
      double yv = (double)acc[i][j];
      sy += yv; sq += yv*yv;
    }
    #pragma unroll
    for (int s = 1; s < 16; s <<= 1){
      sy += __shfl_xor(sy, s);
      sq += __shfl_xor(sq, s);
    }
    if (tx == 0){
      int o = o0 + ty*8 + i;
      atomicAdd(&s1b[o], sy);
      atomicAdd(&s2b[o], sq);
    }
  }
}

// gmax/gavg + broadcast; scale/shift computed per block from fused stats
__global__ __launch_bounds__(256) void k_final5_v2(const float* __restrict__ y5,
                                                   const double* __restrict__ s1b,
                                                   const double* __restrict__ s2b,
                                                   const float* __restrict__ g,
                                                   const float* __restrict__ bb,
                                                   float* __restrict__ out){
  int o = blockIdx.x, b = blockIdx.y;
  __shared__ double smx[256], ssm[256];
  double M = (double)((size_t)BB*NN);
  double mean = s1b[o]/M;
  double var  = s2b[o]/M - mean*mean;
  double sc = (double)g[o]/sqrt(var + EPSD);
  double sh = (double)bb[o] - mean*sc;
  double mx = -INFINITY, sm = 0.0;
  const float* yrow = y5 + ((size_t)b*1024 + o)*NN;
  for (int n = threadIdx.x; n < NN; n += 256){
    double z = sc*(double)yrow[n] + sh;
    z = z > 0.0 ? z : SLOPED*z;
    mx = fmax(mx, z); sm += z;
  }
  smx[threadIdx.x] = mx; ssm[threadIdx.x] = sm;
  __syncthreads();
  for (int s = 128; s > 0; s >>= 1){
    if (threadIdx.x < s){
      smx[threadIdx.x] = fmax(smx[threadIdx.x], smx[threadIdx.x+s]);
      ssm[threadIdx.x] += ssm[threadIdx.x+s];
    }
    __syncthreads();
  }
  float vg = (float)smx[0];
  float va = (float)(ssm[0]*(1.0/NN));
  float* ob = out + (size_t)b*OCN;
  for (int n = threadIdx.x; n < NN; n += 256){
    ob[(size_t)o*NN + n] = vg;
    ob[(size_t)(1024+o)*NN + n] = va;
  }
}

extern "C" void kernel_launch(void* const* d_in, const int* in_sizes, int n_in,
                              void* d_out, int out_size, void* d_ws, size_t ws_size,
                              hipStream_t stream){
  const float* xyz = (const float*)d_in[0];
  float* out = (float*)d_out;
  float* ws  = (float*)d_ws;

  const float* Wp[5] = {(const float*)d_in[1],(const float*)d_in[4],(const float*)d_in[7],(const float*)d_in[10],(const float*)d_in[13]};
  const float* Gp[5] = {(const float*)d_in[2],(const float*)d_in[5],(const float*)d_in[8],(const float*)d_in[11],(const float*)d_in[14]};
  const float* Bp[5] = {(const float*)d_in[3],(const float*)d_in[6],(const float*)d_in[9],(const float*)d_in[12],(const float*)d_in[15]};
  int Cin[4]  = {3, 64, 64, 128};
  int Oc[4]   = {64, 64, 128, 257};
  int xinc[4] = {2048, 2051, 2115, 2179};
  int xoutc[4]= {2051, 2115, 2179, 2307};
  int woff[4] = {0, 192, 4288, 12480};

  float* ymx  = ws + WS_YMX;
  float* ymn  = ws + WS_YMN;
  float* u    = ws + WS_U;
  float* v    = ws + WS_V;
  int*   idx  = (int*)(ws + WS_IDX);
  float* xx   = ws + WS_XX;
  float* wtf  = ws + WS_WTF;
  float* wtd  = ws + WS_WTD;
  float* w5t  = ws + WS_W5T;
  float* y5   = ws + WS_Y5;
  double* s1d = (double*)(ws + WS_S1);
  double* s2d = (double*)(ws + WS_S2);
  double* s1b = (double*)(ws + WS_SC);
  double* s2b = (double*)(ws + WS_SH);

  k_prep_x0<<<cdiv(BB*NN,256), 256, 0, stream>>>(xyz, out);
  k_wt_all <<<cdiv(513*1024,256), 256, 0, stream>>>(Wp[0], Wp[1], Wp[2], Wp[3], Wp[4], wtf, wtd, w5t, s1b, s2b);

  for (int t = 0; t < 4; t++){
    int C = Cin[t], O = Oc[t];
    const float* xin = out + (size_t)xinc[t]*NN;
    k_xx32<<<dim3(NN/256, BB), 256, 0, stream>>>(xin, C, OCN, xx, s1d, s2d);
    int OT = (O <= 64) ? 64 : ((O <= 128) ? 128 : 256);
    for (int bg = 0; bg < 2; bg++){
      k_pd4  <<<dim3(NN/128, NN/128, 4), 256, 0, stream>>>(xin, C, OCN, bg*4, xx, ws,
               (unsigned long long)WS_PD, (unsigned long long)WS_YMX,
               (unsigned long long)WS_YMN, (unsigned long long)WS_U);
      k_topk4<<<dim3(NN/4, 4), 256, 0, stream>>>(ws,
               (unsigned long long)WS_PD, (unsigned long long)WS_YMX,
               (unsigned long long)WS_YMN, (unsigned long long)WS_U,
               bg*4, idx);
    }
    k_gemm_uv<<<dim3(cdiv(O,TS), NN/TS, BB), 256, 0, stream>>>(xin, C, O, OCN, wtf + woff[t], wtd + woff[t], u, v);
    k_passB  <<<dim3(NN/NT, BB), 256, 0, stream>>>(u, v, idx, O, OT, ymx, ymn, s1d, s2d);
    k_passD  <<<dim3(cdiv(O,TS), NN/TS, BB), 256, 0, stream>>>(ymx, ymn, s1d, s2d, Gp[t], Bp[t], O,
               (double)((size_t)BB*NN*KK), out + (size_t)xoutc[t]*NN);
  }

  // ---- layer 5 (1x1 conv 513 -> 1024, fused BN stats) + global pooling ----
  k_conv5g<<<dim3(1024/128, NN/128, BB), 256, 0, stream>>>(out + (size_t)2051*NN, w5t, y5, s1b, s2b);
  k_final5_v2<<<dim3(1024, BB), 256, 0, stream>>>(y5, s1b, s2b, Gp[4], Bp[4], out);
}

// Round 21
// 2397.827 us; speedup vs baseline: 1.2121x; 1.0040x over previous
//
#include <hip/hip_runtime.h>
#include <math.h>

#define BB 8
#define NN 2048
#define KK 20
#define OCH 2564
#define OCN ((size_t)OCH*NN)
#define EPSD 1e-5
#define SLOPED 0.2
#define TS 64

// ---------------- ws layout (float offsets) — ALL DISJOINT while alive ----
// During KNN phase (pd/topk), ymx/ymn/u are dead => used as extra pd buffers.
// y5 (B*1024*N = 16,777,216 f32) overlays PD/YMX/YMN/U at layer 5 (all dead).
// WS_SC/WS_SH are repurposed as layer-5 f64 stat accumulators (zeroed in k_wt_all).
#define WS_PD   ((size_t)0)
#define WS_YMX  ((size_t)4194304)
#define WS_YMN  ((size_t)8404992)
#define WS_U    ((size_t)12615680)
#define WS_V    ((size_t)16826368)
#define WS_IDX  ((size_t)21037056)
#define WS_XX   ((size_t)21364736)
#define WS_WTF  ((size_t)21381120)   // 45376 floats, per-layer offsets {0,192,4288,12480}
#define WS_WTD  ((size_t)21426496)   // 45376
#define WS_W5T  ((size_t)21471872)   // 525312
#define WS_Y5   ((size_t)0)
#define WS_S1   ((size_t)21997184)   // 1024 doubles (layers 1-4)
#define WS_S2   (WS_S1 + 2048)
#define WS_SC   (WS_S2 + 2048)       // 1024 doubles: layer-5 s1 accumulator
#define WS_SH   (WS_SC + 2048)       // 1024 doubles: layer-5 s2 accumulator

static inline int cdiv(int a, int b){ return (a+b-1)/b; }

// out[b, 2048+c, n] = xyz[b,n,c]  (features live in `out`; no separate copies)
__global__ void k_prep_x0(const float* __restrict__ xyz, float* __restrict__ out){
  int id = blockIdx.x*256 + threadIdx.x;
  if (id >= BB*NN) return;
  int b = id / NN, n = id % NN;
  const float* p = xyz + ((size_t)b*NN + n)*3;
  float* o = out + (size_t)b*OCN + (size_t)2048*NN + n;
  o[0] = p[0]; o[(size_t)NN] = p[1]; o[2*(size_t)NN] = p[2];
}

// one-shot weight transpose for all 5 layers + zero layer-5 stat accumulators
__global__ void k_wt_all(const float* __restrict__ W1, const float* __restrict__ W2,
                         const float* __restrict__ W3, const float* __restrict__ W4,
                         const float* __restrict__ W5,
                         float* __restrict__ wtf, float* __restrict__ wtd,
                         float* __restrict__ w5t,
                         double* __restrict__ s1b, double* __restrict__ s2b){
  int id = blockIdx.x*256 + threadIdx.x;
  if (id < 1024){ s1b[id] = 0.0; s2b[id] = 0.0; }
  if (id < 513*1024){
    int c = id / 1024, o = id % 1024;
    w5t[(size_t)c*1024 + o] = W5[(size_t)o*513 + c];
  }
  if (id < 45376){
    const float* W; int C, O; int base;
    if (id < 192)        { W = W1; C = 3;   O = 64;  base = 0; }
    else if (id < 4288)  { W = W2; C = 64;  O = 64;  base = 192; }
    else if (id < 12480) { W = W3; C = 64;  O = 128; base = 4288; }
    else                 { W = W4; C = 128; O = 257; base = 12480; }
    int r = id - base;
    int c = r / O, o = r % O;
    float wf = W[(size_t)o*(2*C) + c];
    float wc = W[(size_t)o*(2*C) + C + c];
    wtf[base + (size_t)c*O + o] = wf;
    wtd[base + (size_t)c*O + o] = wc - wf;
  }
}

// ---- KNN arithmetic: per-output chains validated round 8 (canonical f32) ----
// block (0,0) zeroes s1/s2 for this layer
__global__ void k_xx32(const float* __restrict__ x, int C, size_t bs, float* __restrict__ xx,
                       double* __restrict__ s1, double* __restrict__ s2){
  if (blockIdx.x == 0 && blockIdx.y == 0){
    int t = threadIdx.x;
    #pragma unroll
    for (int i=0;i<4;i++){ s1[t*4+i] = 0.0; s2[t*4+i] = 0.0; }
  }
  int b = blockIdx.y;
  int n = blockIdx.x*256 + threadIdx.x;
  const float* p = x + (size_t)b*bs + n;
  float a;
  if (C <= 8){
    a = 0.f;
    for (int c = 0; c < C; c++){ float v = p[(size_t)c*NN]; float s = v*v; a = a + s; }
  } else {
    float r0,r1,r2,r3,r4,r5,r6,r7;
    { float v;
      v = p[0];            r0 = v*v;
      v = p[(size_t)1*NN]; r1 = v*v;
      v = p[(size_t)2*NN]; r2 = v*v;
      v = p[(size_t)3*NN]; r3 = v*v;
      v = p[(size_t)4*NN]; r4 = v*v;
      v = p[(size_t)5*NN]; r5 = v*v;
      v = p[(size_t)6*NN]; r6 = v*v;
      v = p[(size_t)7*NN]; r7 = v*v;
    }
    for (int i = 8; i < C; i += 8){
      float v;
      v = p[(size_t)(i+0)*NN]; r0 = r0 + v*v;
      v = p[(size_t)(i+1)*NN]; r1 = r1 + v*v;
      v = p[(size_t)(i+2)*NN]; r2 = r2 + v*v;
      v = p[(size_t)(i+3)*NN]; r3 = r3 + v*v;
      v = p[(size_t)(i+4)*NN]; r4 = r4 + v*v;
      v = p[(size_t)(i+5)*NN]; r5 = r5 + v*v;
      v = p[(size_t)(i+6)*NN]; r6 = r6 + v*v;
      v = p[(size_t)(i+7)*NN]; r7 = r7 + v*v;
    }
    a = ((r0+r1)+(r2+r3)) + ((r4+r5)+(r6+r7));
  }
  xx[b*NN + n] = a;
}

// 128x128 tile, 4 batches via blockIdx.z -> 4 disjoint pd buffers.
// Per-output fmaf chain identical to validated version (bit-exact).
// NOTE r18: fusing pd+topk (no pd materialization) REGRESSED 655us/layer —
// pd round-trip is L2/L3-resident and ~free; keep the separate pipeline.
__global__ __launch_bounds__(256) void k_pd4(const float* __restrict__ x, int C, size_t bs, int b0,
                     const float* __restrict__ xx, float* __restrict__ wsbase,
                     unsigned long long o0, unsigned long long o1,
                     unsigned long long o2, unsigned long long o3){
  int z = blockIdx.z;
  unsigned long long off = (z==0)?o0:((z==1)?o1:((z==2)?o2:o3));
  float* pd = wsbase + off;
  int b = b0 + z;
  __shared__ float As[8][128];
  __shared__ float Bs[8][128];
  int n0 = blockIdx.y*128, m0 = blockIdx.x*128;
  int tid = threadIdx.x;
  int ty = tid / 16, tx = tid % 16;
  const float* xb = x + (size_t)b*bs;
  float acc[8][8] = {};
  for (int c0 = 0; c0 < C; c0 += 8){
    #pragma unroll
    for (int rr = 0; rr < 4; rr++){
      int t2 = tid + rr*256;
      int c = t2 >> 7, col = t2 & 127;
      int cc = c0 + c;
      float av = 0.f, bv = 0.f;
      if (cc < C){ av = xb[(size_t)cc*NN + n0 + col]; bv = xb[(size_t)cc*NN + m0 + col]; }
      As[c][col] = av; Bs[c][col] = bv;
    }
    __syncthreads();
    #pragma unroll
    for (int c = 0; c < 8; c++){
      float4 a0 = *reinterpret_cast<const float4*>(&As[c][ty*8]);
      float4 a1 = *reinterpret_cast<const float4*>(&As[c][ty*8+4]);
      float4 b0v = *reinterpret_cast<const float4*>(&Bs[c][tx*4]);
      float4 b1v = *reinterpret_cast<const float4*>(&Bs[c][64 + tx*4]);
      float a[8]  = {a0.x,a0.y,a0.z,a0.w,a1.x,a1.y,a1.z,a1.w};
      float bv[8] = {b0v.x,b0v.y,b0v.z,b0v.w,b1v.x,b1v.y,b1v.z,b1v.w};
      #pragma unroll
      for (int i=0;i<8;i++)
        #pragma unroll
        for (int j=0;j<8;j++)
          acc[i][j] = fmaf(a[i], bv[j], acc[i][j]);
    }
    __syncthreads();
  }
  const float* xxb = xx + b*NN;
  float xm0[4], xm1[4];
  #pragma unroll
  for (int j=0;j<4;j++){ xm0[j] = xxb[m0 + tx*4 + j]; xm1[j] = xxb[m0 + 64 + tx*4 + j]; }
  #pragma unroll
  for (int i=0;i<8;i++){
    int n = n0 + ty*8 + i;
    float xn = xxb[n];
    float4 v0, v1;
    v0.x = (2.f*acc[i][0] - xn) - xm0[0];
    v0.y = (2.f*acc[i][1] - xn) - xm0[1];
    v0.z = (2.f*acc[i][2] - xn) - xm0[2];
    v0.w = (2.f*acc[i][3] - xn) - xm0[3];
    v1.x = (2.f*acc[i][4] - xn) - xm1[0];
    v1.y = (2.f*acc[i][5] - xn) - xm1[1];
    v1.z = (2.f*acc[i][6] - xn) - xm1[2];
    v1.w = (2.f*acc[i][7] - xn) - xm1[3];
    *reinterpret_cast<float4*>(&pd[(size_t)n*NN + m0 + tx*4])      = v0;
    *reinterpret_cast<float4*>(&pd[(size_t)n*NN + m0 + 64 + tx*4]) = v1;
  }
}

// deterministic top-20, 4 batches via blockIdx.y; set ≡ validated scans.
__global__ __launch_bounds__(256) void k_topk4(const float* __restrict__ wsbase,
                     unsigned long long o0, unsigned long long o1,
                     unsigned long long o2, unsigned long long o3,
                     int b0, int* __restrict__ idx){
  int z = blockIdx.y;
  unsigned long long off = (z==0)?o0:((z==1)?o1:((z==2)?o2:o3));
  const float* pdb = wsbase + off;
  int b = b0 + z;
  int lane = threadIdx.x & 63;
  int w = threadIdx.x >> 6;
  int n = blockIdx.x*4 + w;
  const float* row = pdb + (size_t)n*NN;
  float vals[KK]; int inds[KK];
  #pragma unroll
  for (int i=0;i<KK;i++){ vals[i] = -INFINITY; inds[i] = NN; }
  for (int c = 0; c < NN/64; c++){
    int m = c*64 + lane;
    float v = row[m];
    if (v > vals[KK-1]){
      #pragma unroll
      for (int i=KK-1;i>0;--i){
        if (vals[i-1] < v){ vals[i]=vals[i-1]; inds[i]=inds[i-1]; }
      }
      bool done = false;
      #pragma unroll
      for (int i=0;i<KK;i++){
        bool pl = (!done) && (vals[i] < v);
        if (pl){ vals[i]=v; inds[i]=m; done=true; }
      }
    }
  }
  int* op = idx + ((size_t)b*NN + n)*KK;
  #pragma unroll 1
  for (int r = 0; r < KK; r++){
    float bv = vals[0]; int bi = inds[0];
    #pragma unroll
    for (int s = 1; s < 64; s <<= 1){
      float ov = __shfl_xor(bv, s);
      int   oi = __shfl_xor(bi, s);
      if (ov > bv || (ov == bv && oi < bi)){ bv = ov; bi = oi; }
    }
    if (inds[0] == bi){
      #pragma unroll
      for (int i=0;i<KK-1;i++){ vals[i]=vals[i+1]; inds[i]=inds[i+1]; }
      vals[KK-1] = -INFINITY; inds[KK-1] = NN;
    }
    if (lane == 0) op[r] = bi;
  }
}

// u[(b*N+n)*O+o] = sum_c wtf[c][o]*x; v with wtd
// (all batches, f64 accumulate — REQUIRED: u/v feed next-layer KNN features;
//  f32 accumulation here flipped a KNN boundary in round 13. DO NOT TOUCH.)
__global__ __launch_bounds__(256) void k_gemm_uv(
    const float* __restrict__ x, int C, int O, size_t bs,
    const float* __restrict__ wtf, const float* __restrict__ wtd,
    float* __restrict__ u, float* __restrict__ v){
  __shared__ float Xs[8][TS];
  __shared__ float Wfs[8][TS];
  __shared__ float Wds[8][TS];
  int b = blockIdx.z;
  int n0 = blockIdx.y*TS, o0 = blockIdx.x*TS;
  int tid = threadIdx.x, tx = tid%16, ty = tid/16;
  const float* xb = x + (size_t)b*bs;
  double au[4][4] = {};
  double av[4][4] = {};
  for (int c0 = 0; c0 < C; c0 += 8){
    int r = tid/64, col = tid%64;
    #pragma unroll
    for (int rr=0;rr<2;rr++){
      int c = c0 + r + rr*4;
      float xv=0.f, wfv=0.f, wdv=0.f;
      if (c < C){
        xv = xb[(size_t)c*NN + n0 + col];
        if (o0+col < O){
          wfv = wtf[(size_t)c*O + o0+col];
          wdv = wtd[(size_t)c*O + o0+col];
        }
      }
      Xs[r+rr*4][col]=xv; Wfs[r+rr*4][col]=wfv; Wds[r+rr*4][col]=wdv;
    }
    __syncthreads();
    #pragma unroll
    for (int c=0;c<8;c++){
      double a[4], f[4], d[4];
      #pragma unroll
      for (int i=0;i<4;i++) a[i] = (double)Xs[c][ty*4+i];
      #pragma unroll
      for (int j=0;j<4;j++) f[j] = (double)Wfs[c][tx*4+j];
      #pragma unroll
      for (int j=0;j<4;j++) d[j] = (double)Wds[c][tx*4+j];
      #pragma unroll
      for (int i=0;i<4;i++)
        #pragma unroll
        for (int j=0;j<4;j++){
          au[i][j] = fma(a[i], f[j], au[i][j]);
          av[i][j] = fma(a[i], d[j], av[i][j]);
        }
    }
    __syncthreads();
  }
  #pragma unroll
  for (int i=0;i<4;i++){
    int n = n0 + ty*4 + i;
    #pragma unroll
    for (int j=0;j<4;j++){
      int o = o0 + tx*4 + j;
      if (o < O){
        u[((size_t)b*NN + n)*O + o] = (float)au[i][j];
        v[((size_t)b*NN + n)*O + o] = (float)av[i][j];
      }
    }
  }
}

// gather: running max/min of y=u[idx]+v; f64 stats atomics (all batches)
#define NT 32
__global__ __launch_bounds__(256) void k_passB(
  const float* __restrict__ u, const float* __restrict__ v, const int* __restrict__ idx,
  int O, int OT, float* __restrict__ ymax, float* __restrict__ ymin,
  double* __restrict__ s1, double* __restrict__ s2){
  __shared__ int ids[NT*KK];
  int b = blockIdx.y, n0 = blockIdx.x*NT;
  int tid = threadIdx.x;
  for (int t = tid; t < NT*KK; t += 256) ids[t] = idx[((size_t)b*NN + n0)*KK + t];
  __syncthreads();
  int nsplit = 256/OT;
  int ob = tid % OT, ns = tid / OT;
  int nper = NT / nsplit;
  const float* ub = u + (size_t)b*NN*O;
  const float* vb = v + (size_t)b*NN*O;
  for (int o = ob; o < O; o += 256){
    double s1p = 0.0, s2p = 0.0;
    for (int ni = ns*nper; ni < (ns+1)*nper; ni++){
      double su=0.0, sq=0.0;
      float mx=-INFINITY, mn=INFINITY;
      #pragma unroll
      for (int k=0;k<KK;k++){
        int j = ids[ni*KK + k];
        float uu = ub[(size_t)j*O + o];
        double ud = (double)uu;
        su += ud; sq += ud*ud;
        mx = fmaxf(mx, uu); mn = fminf(mn, uu);
      }
      float vv = vb[(size_t)(n0+ni)*O + o];
      double vd = (double)vv;
      s1p += su + (double)KK*vd;
      s2p += sq + 2.0*vd*su + (double)KK*vd*vd;
      size_t yo = ((size_t)b*NN + n0 + ni)*O + o;
      ymax[yo] = mx + vv; ymin[yo] = mn + vv;
    }
    atomicAdd(&s1[o], s1p);
    atomicAdd(&s2[o], s2p);
  }
}

// affine+lrelu (pick ymax/ymin by sign of scale), transpose -> (b,o,n).
// scale/shift computed in-block from s1/s2 (identical f64 expr as old stats_fin).
__global__ __launch_bounds__(256) void k_passD(const float* __restrict__ ymax,
  const float* __restrict__ ymin, const double* __restrict__ s1,
  const double* __restrict__ s2, const float* __restrict__ g,
  const float* __restrict__ bb, int O, double M, float* __restrict__ xout){
  __shared__ float t[64][65];
  __shared__ double s_sc[64], s_sh[64];
  int b = blockIdx.z, n0 = blockIdx.y*64, o0 = blockIdx.x*64;
  int tid = threadIdx.x;
  if (tid < 64){
    int o = o0 + tid;
    double sc = 0.0, sh = 0.0;
    if (o < O){
      double mean = s1[o]/M;
      double var  = s2[o]/M - mean*mean;
      sc = (double)g[o] / sqrt(var + EPSD);
      sh = (double)bb[o] - mean*sc;
    }
    s_sc[tid] = sc; s_sh[tid] = sh;
  }
  __syncthreads();
  int col = tid % 64, rr = tid / 64;
  int o = o0 + col;
  bool ov = (o < O);
  double sc = s_sc[col];
  double sh = s_sh[col];
  const float* src = (sc >= 0.0) ? ymax : ymin;
  for (int p = 0; p < 16; p++){
    int n = n0 + p*4 + rr;
    float y = ov ? src[((size_t)b*NN + n)*O + o] : 0.f;
    double z = sc*(double)y + sh;
    z = z > 0.0 ? z : SLOPED*z;
    t[p*4+rr][col] = (float)z;
  }
  __syncthreads();
  float* xb = xout + (size_t)b*OCN;
  for (int p = 0; p < 16; p++){
    int row = p*4 + rr;
    if (o0 + row < O) xb[(size_t)(o0+row)*NN + n0 + col] = t[col][row];
  }
}

// layer-5 conv as tiled f32 GEMM, 64(o)x128(n) tile (r21: grid-starved at
// 128x128 — 4 blocks/CU, occ 22%; halving the o-tile doubles resident blocks).
// Per-output fmaf chain (c ascending, zero-pad no-ops) unchanged -> y5 bit-identical.
// Fused BN-stat partials as before (4 rows/thread now).
__global__ __launch_bounds__(256) void k_conv5g(const float* __restrict__ xf,
                                                const float* __restrict__ w5t,
                                                float* __restrict__ y5,
                                                double* __restrict__ s1b,
                                                double* __restrict__ s2b){
  __shared__ float Wsh[8][64];
  __shared__ float Xs[8][128];
  int o0 = blockIdx.x*64, n0 = blockIdx.y*128, b = blockIdx.z;
  int tid = threadIdx.x;
  int ty = tid / 16, tx = tid % 16;
  const float* xb = xf + (size_t)b*OCN;
  float acc[4][8] = {};
  for (int c0 = 0; c0 < 513; c0 += 8){
    #pragma unroll
    for (int rr = 0; rr < 2; rr++){
      int t2 = tid + rr*256;
      int c = t2 >> 6, col = t2 & 63;
      int cc = c0 + c;
      Wsh[c][col] = (cc < 513) ? w5t[(size_t)cc*1024 + o0 + col] : 0.f;
    }
    #pragma unroll
    for (int rr = 0; rr < 4; rr++){
      int t2 = tid + rr*256;
      int c = t2 >> 7, col = t2 & 127;
      int cc = c0 + c;
      Xs[c][col] = (cc < 513) ? xb[(size_t)cc*NN + n0 + col] : 0.f;
    }
    __syncthreads();
    #pragma unroll
    for (int c = 0; c < 8; c++){
      float4 w0 = *reinterpret_cast<const float4*>(&Wsh[c][ty*4]);
      float4 x0 = *reinterpret_cast<const float4*>(&Xs[c][tx*4]);
      float4 x1 = *reinterpret_cast<const float4*>(&Xs[c][64 + tx*4]);
      float wr[4] = {w0.x,w0.y,w0.z,w0.w};
      float xr[8] = {x0.x,x0.y,x0.z,x0.w,x1.x,x1.y,x1.z,x1.w};
      #pragma unroll
      for (int i=0;i<4;i++)
        #pragma unroll
        for (int j=0;j<8;j++)
          acc[i][j] = fmaf(wr[i], xr[j], acc[i][j]);
    }
    __syncthreads();
  }
  #pragma unroll
  for (int i=0;i<4;i++){
    int o = o0 + ty*4 + i;
    float* yr = y5 + ((size_t)b*1024 + o)*NN;
    float4 v0 = {acc[i][0], acc[i][1], acc[i][2], acc[i][3]};
    float4 v1 = {acc[i][4], acc[i][5], acc[i][6], acc[i][7]};
    *reinterpret_cast<float4*>(&yr[n0 + tx*4])      = v0;
    *reinterpret_cast<float4*>(&yr[n0 + 64 + tx*4]) = v1;
  }
  // fused BN-stat partials: reduce this block's 128-n slice per channel.
  // ty group = 16 consecutive lanes within its wave; xor s<16 reduces tx-groups.
  #pragma unroll
  for (int i=0;i<4;i++){
    double sy = 0.0, sq = 0.0;
    #pragma unroll
    for (int j=0;j<8;j++){
      double yv = (double)acc[i][j];
      sy += yv; sq += yv*yv;
    }
    #pragma unroll
    for (int s = 1; s < 16; s <<= 1){
      sy += __shfl_xor(sy, s);
      sq += __shfl_xor(sq, s);
    }
    if (tx == 0){
      int o = o0 + ty*4 + i;
      atomicAdd(&s1b[o], sy);
      atomicAdd(&s2b[o], sq);
    }
  }
}

// gmax/gavg + broadcast; scale/shift computed per block from fused stats
__global__ __launch_bounds__(256) void k_final5_v2(const float* __restrict__ y5,
                                                   const double* __restrict__ s1b,
                                                   const double* __restrict__ s2b,
                                                   const float* __restrict__ g,
                                                   const float* __restrict__ bb,
                                                   float* __restrict__ out){
  int o = blockIdx.x, b = blockIdx.y;
  __shared__ double smx[256], ssm[256];
  double M = (double)((size_t)BB*NN);
  double mean = s1b[o]/M;
  double var  = s2b[o]/M - mean*mean;
  double sc = (double)g[o]/sqrt(var + EPSD);
  double sh = (double)bb[o] - mean*sc;
  double mx = -INFINITY, sm = 0.0;
  const float* yrow = y5 + ((size_t)b*1024 + o)*NN;
  for (int n = threadIdx.x; n < NN; n += 256){
    double z = sc*(double)yrow[n] + sh;
    z = z > 0.0 ? z : SLOPED*z;
    mx = fmax(mx, z); sm += z;
  }
  smx[threadIdx.x] = mx; ssm[threadIdx.x] = sm;
  __syncthreads();
  for (int s = 128; s > 0; s >>= 1){
    if (threadIdx.x < s){
      smx[threadIdx.x] = fmax(smx[threadIdx.x], smx[threadIdx.x+s]);
      ssm[threadIdx.x] += ssm[threadIdx.x+s];
    }
    __syncthreads();
  }
  float vg = (float)smx[0];
  float va = (float)(ssm[0]*(1.0/NN));
  float* ob = out + (size_t)b*OCN;
  for (int n = threadIdx.x; n < NN; n += 256){
    ob[(size_t)o*NN + n] = vg;
    ob[(size_t)(1024+o)*NN + n] = va;
  }
}

extern "C" void kernel_launch(void* const* d_in, const int* in_sizes, int n_in,
                              void* d_out, int out_size, void* d_ws, size_t ws_size,
                              hipStream_t stream){
  const float* xyz = (const float*)d_in[0];
  float* out = (float*)d_out;
  float* ws  = (float*)d_ws;

  const float* Wp[5] = {(const float*)d_in[1],(const float*)d_in[4],(const float*)d_in[7],(const float*)d_in[10],(const float*)d_in[13]};
  const float* Gp[5] = {(const float*)d_in[2],(const float*)d_in[5],(const float*)d_in[8],(const float*)d_in[11],(const float*)d_in[14]};
  const float* Bp[5] = {(const float*)d_in[3],(const float*)d_in[6],(const float*)d_in[9],(const float*)d_in[12],(const float*)d_in[15]};
  int Cin[4]  = {3, 64, 64, 128};
  int Oc[4]   = {64, 64, 128, 257};
  int xinc[4] = {2048, 2051, 2115, 2179};
  int xoutc[4]= {2051, 2115, 2179, 2307};
  int woff[4] = {0, 192, 4288, 12480};

  float* ymx  = ws + WS_YMX;
  float* ymn  = ws + WS_YMN;
  float* u    = ws + WS_U;
  float* v    = ws + WS_V;
  int*   idx  = (int*)(ws + WS_IDX);
  float* xx   = ws + WS_XX;
  float* wtf  = ws + WS_WTF;
  float* wtd  = ws + WS_WTD;
  float* w5t  = ws + WS_W5T;
  float* y5   = ws + WS_Y5;
  double* s1d = (double*)(ws + WS_S1);
  double* s2d = (double*)(ws + WS_S2);
  double* s1b = (double*)(ws + WS_SC);
  double* s2b = (double*)(ws + WS_SH);

  k_prep_x0<<<cdiv(BB*NN,256), 256, 0, stream>>>(xyz, out);
  k_wt_all <<<cdiv(513*1024,256), 256, 0, stream>>>(Wp[0], Wp[1], Wp[2], Wp[3], Wp[4], wtf, wtd, w5t, s1b, s2b);

  for (int t = 0; t < 4; t++){
    int C = Cin[t], O = Oc[t];
    const float* xin = out + (size_t)xinc[t]*NN;
    k_xx32<<<dim3(NN/256, BB), 256, 0, stream>>>(xin, C, OCN, xx, s1d, s2d);
    int OT = (O <= 64) ? 64 : ((O <= 128) ? 128 : 256);
    for (int bg = 0; bg < 2; bg++){
      k_pd4  <<<dim3(NN/128, NN/128, 4), 256, 0, stream>>>(xin, C, OCN, bg*4, xx, ws,
               (unsigned long long)WS_PD, (unsigned long long)WS_YMX,
               (unsigned long long)WS_YMN, (unsigned long long)WS_U);
      k_topk4<<<dim3(NN/4, 4), 256, 0, stream>>>(ws,
               (unsigned long long)WS_PD, (unsigned long long)WS_YMX,
               (unsigned long long)WS_YMN, (unsigned long long)WS_U,
               bg*4, idx);
    }
    k_gemm_uv<<<dim3(cdiv(O,TS), NN/TS, BB), 256, 0, stream>>>(xin, C, O, OCN, wtf + woff[t], wtd + woff[t], u, v);
    k_passB  <<<dim3(NN/NT, BB), 256, 0, stream>>>(u, v, idx, O, OT, ymx, ymn, s1d, s2d);
    k_passD  <<<dim3(cdiv(O,TS), NN/TS, BB), 256, 0, stream>>>(ymx, ymn, s1d, s2d, Gp[t], Bp[t], O,
               (double)((size_t)BB*NN*KK), out + (size_t)xoutc[t]*NN);
  }

  // ---- layer 5 (1x1 conv 513 -> 1024, fused BN stats) + global pooling ----
  k_conv5g<<<dim3(1024/64, NN/128, BB), 256, 0, stream>>>(out + (size_t)2051*NN, w5t, y5, s1b, s2b);
  k_final5_v2<<<dim3(1024, BB), 256, 0, stream>>>(y5, s1b, s2b, Gp[4], Bp[4], out);
}

// Round 22
// 2349.947 us; speedup vs baseline: 1.2368x; 1.0204x over previous
//
#include <hip/hip_runtime.h>
#include <math.h>

#define BB 8
#define NN 2048
#define KK 20
#define OCH 2564
#define OCN ((size_t)OCH*NN)
#define EPSD 1e-5
#define SLOPED 0.2
#define TS 64

// ---------------- ws layout (float offsets) — ALL DISJOINT while alive ----
// During KNN phase (pd/topk), ymx/ymn/u are dead => used as extra pd buffers.
// y5 (B*1024*N = 16,777,216 f32) overlays PD/YMX/YMN/U at layer 5 (all dead).
// WS_SC/WS_SH are repurposed as layer-5 f64 stat accumulators (zeroed in k_wt_all).
#define WS_PD   ((size_t)0)
#define WS_YMX  ((size_t)4194304)
#define WS_YMN  ((size_t)8404992)
#define WS_U    ((size_t)12615680)
#define WS_V    ((size_t)16826368)
#define WS_IDX  ((size_t)21037056)
#define WS_XX   ((size_t)21364736)
#define WS_WTF  ((size_t)21381120)   // 45376 floats, per-layer offsets {0,192,4288,12480}
#define WS_WTD  ((size_t)21426496)   // 45376
#define WS_W5T  ((size_t)21471872)   // 525312
#define WS_Y5   ((size_t)0)
#define WS_S1   ((size_t)21997184)   // 1024 doubles (layers 1-4)
#define WS_S2   (WS_S1 + 2048)
#define WS_SC   (WS_S2 + 2048)       // 1024 doubles: layer-5 s1 accumulator
#define WS_SH   (WS_SC + 2048)       // 1024 doubles: layer-5 s2 accumulator

static inline int cdiv(int a, int b){ return (a+b-1)/b; }

// out[b, 2048+c, n] = xyz[b,n,c]  (features live in `out`; no separate copies)
__global__ void k_prep_x0(const float* __restrict__ xyz, float* __restrict__ out){
  int id = blockIdx.x*256 + threadIdx.x;
  if (id >= BB*NN) return;
  int b = id / NN, n = id % NN;
  const float* p = xyz + ((size_t)b*NN + n)*3;
  float* o = out + (size_t)b*OCN + (size_t)2048*NN + n;
  o[0] = p[0]; o[(size_t)NN] = p[1]; o[2*(size_t)NN] = p[2];
}

// one-shot weight transpose for all 5 layers + zero layer-5 stat accumulators
__global__ void k_wt_all(const float* __restrict__ W1, const float* __restrict__ W2,
                         const float* __restrict__ W3, const float* __restrict__ W4,
                         const float* __restrict__ W5,
                         float* __restrict__ wtf, float* __restrict__ wtd,
                         float* __restrict__ w5t,
                         double* __restrict__ s1b, double* __restrict__ s2b){
  int id = blockIdx.x*256 + threadIdx.x;
  if (id < 1024){ s1b[id] = 0.0; s2b[id] = 0.0; }
  if (id < 513*1024){
    int c = id / 1024, o = id % 1024;
    w5t[(size_t)c*1024 + o] = W5[(size_t)o*513 + c];
  }
  if (id < 45376){
    const float* W; int C, O; int base;
    if (id < 192)        { W = W1; C = 3;   O = 64;  base = 0; }
    else if (id < 4288)  { W = W2; C = 64;  O = 64;  base = 192; }
    else if (id < 12480) { W = W3; C = 64;  O = 128; base = 4288; }
    else                 { W = W4; C = 128; O = 257; base = 12480; }
    int r = id - base;
    int c = r / O, o = r % O;
    float wf = W[(size_t)o*(2*C) + c];
    float wc = W[(size_t)o*(2*C) + C + c];
    wtf[base + (size_t)c*O + o] = wf;
    wtd[base + (size_t)c*O + o] = wc - wf;
  }
}

// ---- KNN arithmetic: per-output chains validated round 8 (canonical f32) ----
// block (0,0) zeroes s1/s2 for this layer
__global__ void k_xx32(const float* __restrict__ x, int C, size_t bs, float* __restrict__ xx,
                       double* __restrict__ s1, double* __restrict__ s2){
  if (blockIdx.x == 0 && blockIdx.y == 0){
    int t = threadIdx.x;
    #pragma unroll
    for (int i=0;i<4;i++){ s1[t*4+i] = 0.0; s2[t*4+i] = 0.0; }
  }
  int b = blockIdx.y;
  int n = blockIdx.x*256 + threadIdx.x;
  const float* p = x + (size_t)b*bs + n;
  float a;
  if (C <= 8){
    a = 0.f;
    for (int c = 0; c < C; c++){ float v = p[(size_t)c*NN]; float s = v*v; a = a + s; }
  } else {
    float r0,r1,r2,r3,r4,r5,r6,r7;
    { float v;
      v = p[0];            r0 = v*v;
      v = p[(size_t)1*NN]; r1 = v*v;
      v = p[(size_t)2*NN]; r2 = v*v;
      v = p[(size_t)3*NN]; r3 = v*v;
      v = p[(size_t)4*NN]; r4 = v*v;
      v = p[(size_t)5*NN]; r5 = v*v;
      v = p[(size_t)6*NN]; r6 = v*v;
      v = p[(size_t)7*NN]; r7 = v*v;
    }
    for (int i = 8; i < C; i += 8){
      float v;
      v = p[(size_t)(i+0)*NN]; r0 = r0 + v*v;
      v = p[(size_t)(i+1)*NN]; r1 = r1 + v*v;
      v = p[(size_t)(i+2)*NN]; r2 = r2 + v*v;
      v = p[(size_t)(i+3)*NN]; r3 = r3 + v*v;
      v = p[(size_t)(i+4)*NN]; r4 = r4 + v*v;
      v = p[(size_t)(i+5)*NN]; r5 = r5 + v*v;
      v = p[(size_t)(i+6)*NN]; r6 = r6 + v*v;
      v = p[(size_t)(i+7)*NN]; r7 = r7 + v*v;
    }
    a = ((r0+r1)+(r2+r3)) + ((r4+r5)+(r6+r7));
  }
  xx[b*NN + n] = a;
}

// 64(n)x128(m) tile, 4 batches via blockIdx.z -> 4 disjoint pd buffers.
// r22: was 128x128 (4 blocks/CU, occ ~22%); halving n-tile doubles resident
// blocks (same trick as conv5g r21). Per-output fmaf chain (c ascending,
// zero-pad no-ops, (2f*acc - xx[n]) - xx[m]) unchanged -> pd bit-identical.
// NOTE r18: fusing pd+topk REGRESSED; pd round-trip is L2/L3-resident.
__global__ __launch_bounds__(256) void k_pd4(const float* __restrict__ x, int C, size_t bs, int b0,
                     const float* __restrict__ xx, float* __restrict__ wsbase,
                     unsigned long long o0, unsigned long long o1,
                     unsigned long long o2, unsigned long long o3){
  int z = blockIdx.z;
  unsigned long long off = (z==0)?o0:((z==1)?o1:((z==2)?o2:o3));
  float* pd = wsbase + off;
  int b = b0 + z;
  __shared__ float As[8][64];
  __shared__ float Bs[8][128];
  int n0 = blockIdx.y*64, m0 = blockIdx.x*128;
  int tid = threadIdx.x;
  int ty = tid / 16, tx = tid % 16;
  const float* xb = x + (size_t)b*bs;
  float acc[4][8] = {};
  for (int c0 = 0; c0 < C; c0 += 8){
    #pragma unroll
    for (int rr = 0; rr < 2; rr++){
      int t2 = tid + rr*256;
      int c = t2 >> 6, col = t2 & 63;
      int cc = c0 + c;
      As[c][col] = (cc < C) ? xb[(size_t)cc*NN + n0 + col] : 0.f;
    }
    #pragma unroll
    for (int rr = 0; rr < 4; rr++){
      int t2 = tid + rr*256;
      int c = t2 >> 7, col = t2 & 127;
      int cc = c0 + c;
      Bs[c][col] = (cc < C) ? xb[(size_t)cc*NN + m0 + col] : 0.f;
    }
    __syncthreads();
    #pragma unroll
    for (int c = 0; c < 8; c++){
      float4 a0 = *reinterpret_cast<const float4*>(&As[c][ty*4]);
      float4 b0v = *reinterpret_cast<const float4*>(&Bs[c][tx*4]);
      float4 b1v = *reinterpret_cast<const float4*>(&Bs[c][64 + tx*4]);
      float a[4]  = {a0.x,a0.y,a0.z,a0.w};
      float bv[8] = {b0v.x,b0v.y,b0v.z,b0v.w,b1v.x,b1v.y,b1v.z,b1v.w};
      #pragma unroll
      for (int i=0;i<4;i++)
        #pragma unroll
        for (int j=0;j<8;j++)
          acc[i][j] = fmaf(a[i], bv[j], acc[i][j]);
    }
    __syncthreads();
  }
  const float* xxb = xx + b*NN;
  float xm0[4], xm1[4];
  #pragma unroll
  for (int j=0;j<4;j++){ xm0[j] = xxb[m0 + tx*4 + j]; xm1[j] = xxb[m0 + 64 + tx*4 + j]; }
  #pragma unroll
  for (int i=0;i<4;i++){
    int n = n0 + ty*4 + i;
    float xn = xxb[n];
    float4 v0, v1;
    v0.x = (2.f*acc[i][0] - xn) - xm0[0];
    v0.y = (2.f*acc[i][1] - xn) - xm0[1];
    v0.z = (2.f*acc[i][2] - xn) - xm0[2];
    v0.w = (2.f*acc[i][3] - xn) - xm0[3];
    v1.x = (2.f*acc[i][4] - xn) - xm1[0];
    v1.y = (2.f*acc[i][5] - xn) - xm1[1];
    v1.z = (2.f*acc[i][6] - xn) - xm1[2];
    v1.w = (2.f*acc[i][7] - xn) - xm1[3];
    *reinterpret_cast<float4*>(&pd[(size_t)n*NN + m0 + tx*4])      = v0;
    *reinterpret_cast<float4*>(&pd[(size_t)n*NN + m0 + 64 + tx*4]) = v1;
  }
}

// deterministic top-20, 4 batches via blockIdx.y; set ≡ validated scans.
__global__ __launch_bounds__(256) void k_topk4(const float* __restrict__ wsbase,
                     unsigned long long o0, unsigned long long o1,
                     unsigned long long o2, unsigned long long o3,
                     int b0, int* __restrict__ idx){
  int z = blockIdx.y;
  unsigned long long off = (z==0)?o0:((z==1)?o1:((z==2)?o2:o3));
  const float* pdb = wsbase + off;
  int b = b0 + z;
  int lane = threadIdx.x & 63;
  int w = threadIdx.x >> 6;
  int n = blockIdx.x*4 + w;
  const float* row = pdb + (size_t)n*NN;
  float vals[KK]; int inds[KK];
  #pragma unroll
  for (int i=0;i<KK;i++){ vals[i] = -INFINITY; inds[i] = NN; }
  for (int c = 0; c < NN/64; c++){
    int m = c*64 + lane;
    float v = row[m];
    if (v > vals[KK-1]){
      #pragma unroll
      for (int i=KK-1;i>0;--i){
        if (vals[i-1] < v){ vals[i]=vals[i-1]; inds[i]=inds[i-1]; }
      }
      bool done = false;
      #pragma unroll
      for (int i=0;i<KK;i++){
        bool pl = (!done) && (vals[i] < v);
        if (pl){ vals[i]=v; inds[i]=m; done=true; }
      }
    }
  }
  int* op = idx + ((size_t)b*NN + n)*KK;
  #pragma unroll 1
  for (int r = 0; r < KK; r++){
    float bv = vals[0]; int bi = inds[0];
    #pragma unroll
    for (int s = 1; s < 64; s <<= 1){
      float ov = __shfl_xor(bv, s);
      int   oi = __shfl_xor(bi, s);
      if (ov > bv || (ov == bv && oi < bi)){ bv = ov; bi = oi; }
    }
    if (inds[0] == bi){
      #pragma unroll
      for (int i=0;i<KK-1;i++){ vals[i]=vals[i+1]; inds[i]=inds[i+1]; }
      vals[KK-1] = -INFINITY; inds[KK-1] = NN;
    }
    if (lane == 0) op[r] = bi;
  }
}

// u[(b*N+n)*O+o] = sum_c wtf[c][o]*x; v with wtd
// (all batches, f64 accumulate — REQUIRED: u/v feed next-layer KNN features;
//  f32 accumulation here flipped a KNN boundary in round 13. DO NOT TOUCH.)
__global__ __launch_bounds__(256) void k_gemm_uv(
    const float* __restrict__ x, int C, int O, size_t bs,
    const float* __restrict__ wtf, const float* __restrict__ wtd,
    float* __restrict__ u, float* __restrict__ v){
  __shared__ float Xs[8][TS];
  __shared__ float Wfs[8][TS];
  __shared__ float Wds[8][TS];
  int b = blockIdx.z;
  int n0 = blockIdx.y*TS, o0 = blockIdx.x*TS;
  int tid = threadIdx.x, tx = tid%16, ty = tid/16;
  const float* xb = x + (size_t)b*bs;
  double au[4][4] = {};
  double av[4][4] = {};
  for (int c0 = 0; c0 < C; c0 += 8){
    int r = tid/64, col = tid%64;
    #pragma unroll
    for (int rr=0;rr<2;rr++){
      int c = c0 + r + rr*4;
      float xv=0.f, wfv=0.f, wdv=0.f;
      if (c < C){
        xv = xb[(size_t)c*NN + n0 + col];
        if (o0+col < O){
          wfv = wtf[(size_t)c*O + o0+col];
          wdv = wtd[(size_t)c*O + o0+col];
        }
      }
      Xs[r+rr*4][col]=xv; Wfs[r+rr*4][col]=wfv; Wds[r+rr*4][col]=wdv;
    }
    __syncthreads();
    #pragma unroll
    for (int c=0;c<8;c++){
      double a[4], f[4], d[4];
      #pragma unroll
      for (int i=0;i<4;i++) a[i] = (double)Xs[c][ty*4+i];
      #pragma unroll
      for (int j=0;j<4;j++) f[j] = (double)Wfs[c][tx*4+j];
      #pragma unroll
      for (int j=0;j<4;j++) d[j] = (double)Wds[c][tx*4+j];
      #pragma unroll
      for (int i=0;i<4;i++)
        #pragma unroll
        for (int j=0;j<4;j++){
          au[i][j] = fma(a[i], f[j], au[i][j]);
          av[i][j] = fma(a[i], d[j], av[i][j]);
        }
    }
    __syncthreads();
  }
  #pragma unroll
  for (int i=0;i<4;i++){
    int n = n0 + ty*4 + i;
    #pragma unroll
    for (int j=0;j<4;j++){
      int o = o0 + tx*4 + j;
      if (o < O){
        u[((size_t)b*NN + n)*O + o] = (float)au[i][j];
        v[((size_t)b*NN + n)*O + o] = (float)av[i][j];
      }
    }
  }
}

// gather: running max/min of y=u[idx]+v; f64 stats atomics (all batches)
#define NT 32
__global__ __launch_bounds__(256) void k_passB(
  const float* __restrict__ u, const float* __restrict__ v, const int* __restrict__ idx,
  int O, int OT, float* __restrict__ ymax, float* __restrict__ ymin,
  double* __restrict__ s1, double* __restrict__ s2){
  __shared__ int ids[NT*KK];
  int b = blockIdx.y, n0 = blockIdx.x*NT;
  int tid = threadIdx.x;
  for (int t = tid; t < NT*KK; t += 256) ids[t] = idx[((size_t)b*NN + n0)*KK + t];
  __syncthreads();
  int nsplit = 256/OT;
  int ob = tid % OT, ns = tid / OT;
  int nper = NT / nsplit;
  const float* ub = u + (size_t)b*NN*O;
  const float* vb = v + (size_t)b*NN*O;
  for (int o = ob; o < O; o += 256){
    double s1p = 0.0, s2p = 0.0;
    for (int ni = ns*nper; ni < (ns+1)*nper; ni++){
      double su=0.0, sq=0.0;
      float mx=-INFINITY, mn=INFINITY;
      #pragma unroll
      for (int k=0;k<KK;k++){
        int j = ids[ni*KK + k];
        float uu = ub[(size_t)j*O + o];
        double ud = (double)uu;
        su += ud; sq += ud*ud;
        mx = fmaxf(mx, uu); mn = fminf(mn, uu);
      }
      float vv = vb[(size_t)(n0+ni)*O + o];
      double vd = (double)vv;
      s1p += su + (double)KK*vd;
      s2p += sq + 2.0*vd*su + (double)KK*vd*vd;
      size_t yo = ((size_t)b*NN + n0 + ni)*O + o;
      ymax[yo] = mx + vv; ymin[yo] = mn + vv;
    }
    atomicAdd(&s1[o], s1p);
    atomicAdd(&s2[o], s2p);
  }
}

// affine+lrelu (pick ymax/ymin by sign of scale), transpose -> (b,o,n).
// scale/shift computed in-block from s1/s2 (identical f64 expr as old stats_fin).
__global__ __launch_bounds__(256) void k_passD(const float* __restrict__ ymax,
  const float* __restrict__ ymin, const double* __restrict__ s1,
  const double* __restrict__ s2, const float* __restrict__ g,
  const float* __restrict__ bb, int O, double M, float* __restrict__ xout){
  __shared__ float t[64][65];
  __shared__ double s_sc[64], s_sh[64];
  int b = blockIdx.z, n0 = blockIdx.y*64, o0 = blockIdx.x*64;
  int tid = threadIdx.x;
  if (tid < 64){
    int o = o0 + tid;
    double sc = 0.0, sh = 0.0;
    if (o < O){
      double mean = s1[o]/M;
      double var  = s2[o]/M - mean*mean;
      sc = (double)g[o] / sqrt(var + EPSD);
      sh = (double)bb[o] - mean*sc;
    }
    s_sc[tid] = sc; s_sh[tid] = sh;
  }
  __syncthreads();
  int col = tid % 64, rr = tid / 64;
  int o = o0 + col;
  bool ov = (o < O);
  double sc = s_sc[col];
  double sh = s_sh[col];
  const float* src = (sc >= 0.0) ? ymax : ymin;
  for (int p = 0; p < 16; p++){
    int n = n0 + p*4 + rr;
    float y = ov ? src[((size_t)b*NN + n)*O + o] : 0.f;
    double z = sc*(double)y + sh;
    z = z > 0.0 ? z : SLOPED*z;
    t[p*4+rr][col] = (float)z;
  }
  __syncthreads();
  float* xb = xout + (size_t)b*OCN;
  for (int p = 0; p < 16; p++){
    int row = p*4 + rr;
    if (o0 + row < O) xb[(size_t)(o0+row)*NN + n0 + col] = t[col][row];
  }
}

// layer-5 conv as tiled f32 GEMM, 64(o)x128(n) tile (r21-proven: occ 45%).
// Per-output fmaf chain unchanged -> y5 bit-identical.  Fused BN-stat partials.
__global__ __launch_bounds__(256) void k_conv5g(const float* __restrict__ xf,
                                                const float* __restrict__ w5t,
                                                float* __restrict__ y5,
                                                double* __restrict__ s1b,
                                                double* __restrict__ s2b){
  __shared__ float Wsh[8][64];
  __shared__ float Xs[8][128];
  int o0 = blockIdx.x*64, n0 = blockIdx.y*128, b = blockIdx.z;
  int tid = threadIdx.x;
  int ty = tid / 16, tx = tid % 16;
  const float* xb = xf + (size_t)b*OCN;
  float acc[4][8] = {};
  for (int c0 = 0; c0 < 513; c0 += 8){
    #pragma unroll
    for (int rr = 0; rr < 2; rr++){
      int t2 = tid + rr*256;
      int c = t2 >> 6, col = t2 & 63;
      int cc = c0 + c;
      Wsh[c][col] = (cc < 513) ? w5t[(size_t)cc*1024 + o0 + col] : 0.f;
    }
    #pragma unroll
    for (int rr = 0; rr < 4; rr++){
      int t2 = tid + rr*256;
      int c = t2 >> 7, col = t2 & 127;
      int cc = c0 + c;
      Xs[c][col] = (cc < 513) ? xb[(size_t)cc*NN + n0 + col] : 0.f;
    }
    __syncthreads();
    #pragma unroll
    for (int c = 0; c < 8; c++){
      float4 w0 = *reinterpret_cast<const float4*>(&Wsh[c][ty*4]);
      float4 x0 = *reinterpret_cast<const float4*>(&Xs[c][tx*4]);
      float4 x1 = *reinterpret_cast<const float4*>(&Xs[c][64 + tx*4]);
      float wr[4] = {w0.x,w0.y,w0.z,w0.w};
      float xr[8] = {x0.x,x0.y,x0.z,x0.w,x1.x,x1.y,x1.z,x1.w};
      #pragma unroll
      for (int i=0;i<4;i++)
        #pragma unroll
        for (int j=0;j<8;j++)
          acc[i][j] = fmaf(wr[i], xr[j], acc[i][j]);
    }
    __syncthreads();
  }
  #pragma unroll
  for (int i=0;i<4;i++){
    int o = o0 + ty*4 + i;
    float* yr = y5 + ((size_t)b*1024 + o)*NN;
    float4 v0 = {acc[i][0], acc[i][1], acc[i][2], acc[i][3]};
    float4 v1 = {acc[i][4], acc[i][5], acc[i][6], acc[i][7]};
    *reinterpret_cast<float4*>(&yr[n0 + tx*4])      = v0;
    *reinterpret_cast<float4*>(&yr[n0 + 64 + tx*4]) = v1;
  }
  // fused BN-stat partials
  #pragma unroll
  for (int i=0;i<4;i++){
    double sy = 0.0, sq = 0.0;
    #pragma unroll
    for (int j=0;j<8;j++){
      double yv = (double)acc[i][j];
      sy += yv; sq += yv*yv;
    }
    #pragma unroll
    for (int s = 1; s < 16; s <<= 1){
      sy += __shfl_xor(sy, s);
      sq += __shfl_xor(sq, s);
    }
    if (tx == 0){
      int o = o0 + ty*4 + i;
      atomicAdd(&s1b[o], sy);
      atomicAdd(&s2b[o], sq);
    }
  }
}

// gmax/gavg + broadcast; scale/shift computed per block from fused stats
__global__ __launch_bounds__(256) void k_final5_v2(const float* __restrict__ y5,
                                                   const double* __restrict__ s1b,
                                                   const double* __restrict__ s2b,
                                                   const float* __restrict__ g,
                                                   const float* __restrict__ bb,
                                                   float* __restrict__ out){
  int o = blockIdx.x, b = blockIdx.y;
  __shared__ double smx[256], ssm[256];
  double M = (double)((size_t)BB*NN);
  double mean = s1b[o]/M;
  double var  = s2b[o]/M - mean*mean;
  double sc = (double)g[o]/sqrt(var + EPSD);
  double sh = (double)bb[o] - mean*sc;
  double mx = -INFINITY, sm = 0.0;
  const float* yrow = y5 + ((size_t)b*1024 + o)*NN;
  for (int n = threadIdx.x; n < NN; n += 256){
    double z = sc*(double)yrow[n] + sh;
    z = z > 0.0 ? z : SLOPED*z;
    mx = fmax(mx, z); sm += z;
  }
  smx[threadIdx.x] = mx; ssm[threadIdx.x] = sm;
  __syncthreads();
  for (int s = 128; s > 0; s >>= 1){
    if (threadIdx.x < s){
      smx[threadIdx.x] = fmax(smx[threadIdx.x], smx[threadIdx.x+s]);
      ssm[threadIdx.x] += ssm[threadIdx.x+s];
    }
    __syncthreads();
  }
  float vg = (float)smx[0];
  float va = (float)(ssm[0]*(1.0/NN));
  float* ob = out + (size_t)b*OCN;
  for (int n = threadIdx.x; n < NN; n += 256){
    ob[(size_t)o*NN + n] = vg;
    ob[(size_t)(1024+o)*NN + n] = va;
  }
}

extern "C" void kernel_launch(void* const* d_in, const int* in_sizes, int n_in,
                              void* d_out, int out_size, void* d_ws, size_t ws_size,
                              hipStream_t stream){
  const float* xyz = (const float*)d_in[0];
  float* out = (float*)d_out;
  float* ws  = (float*)d_ws;

  const float* Wp[5] = {(const float*)d_in[1],(const float*)d_in[4],(const float*)d_in[7],(const float*)d_in[10],(const float*)d_in[13]};
  const float* Gp[5] = {(const float*)d_in[2],(const float*)d_in[5],(const float*)d_in[8],(const float*)d_in[11],(const float*)d_in[14]};
  const float* Bp[5] = {(const float*)d_in[3],(const float*)d_in[6],(const float*)d_in[9],(const float*)d_in[12],(const float*)d_in[15]};
  int Cin[4]  = {3, 64, 64, 128};
  int Oc[4]   = {64, 64, 128, 257};
  int xinc[4] = {2048, 2051, 2115, 2179};
  int xoutc[4]= {2051, 2115, 2179, 2307};
  int woff[4] = {0, 192, 4288, 12480};

  float* ymx  = ws + WS_YMX;
  float* ymn  = ws + WS_YMN;
  float* u    = ws + WS_U;
  float* v    = ws + WS_V;
  int*   idx  = (int*)(ws + WS_IDX);
  float* xx   = ws + WS_XX;
  float* wtf  = ws + WS_WTF;
  float* wtd  = ws + WS_WTD;
  float* w5t  = ws + WS_W5T;
  float* y5   = ws + WS_Y5;
  double* s1d = (double*)(ws + WS_S1);
  double* s2d = (double*)(ws + WS_S2);
  double* s1b = (double*)(ws + WS_SC);
  double* s2b = (double*)(ws + WS_SH);

  k_prep_x0<<<cdiv(BB*NN,256), 256, 0, stream>>>(xyz, out);
  k_wt_all <<<cdiv(513*1024,256), 256, 0, stream>>>(Wp[0], Wp[1], Wp[2], Wp[3], Wp[4], wtf, wtd, w5t, s1b, s2b);

  for (int t = 0; t < 4; t++){
    int C = Cin[t], O = Oc[t];
    const float* xin = out + (size_t)xinc[t]*NN;
    k_xx32<<<dim3(NN/256, BB), 256, 0, stream>>>(xin, C, OCN, xx, s1d, s2d);
    int OT = (O <= 64) ? 64 : ((O <= 128) ? 128 : 256);
    for (int bg = 0; bg < 2; bg++){
      k_pd4  <<<dim3(NN/128, NN/64, 4), 256, 0, stream>>>(xin, C, OCN, bg*4, xx, ws,
               (unsigned long long)WS_PD, (unsigned long long)WS_YMX,
               (unsigned long long)WS_YMN, (unsigned long long)WS_U);
      k_topk4<<<dim3(NN/4, 4), 256, 0, stream>>>(ws,
               (unsigned long long)WS_PD, (unsigned long long)WS_YMX,
               (unsigned long long)WS_YMN, (unsigned long long)WS_U,
               bg*4, idx);
    }
    k_gemm_uv<<<dim3(cdiv(O,TS), NN/TS, BB), 256, 0, stream>>>(xin, C, O, OCN, wtf + woff[t], wtd + woff[t], u, v);
    k_passB  <<<dim3(NN/NT, BB), 256, 0, stream>>>(u, v, idx, O, OT, ymx, ymn, s1d, s2d);
    k_passD  <<<dim3(cdiv(O,TS), NN/TS, BB), 256, 0, stream>>>(ymx, ymn, s1d, s2d, Gp[t], Bp[t], O,
               (double)((size_t)BB*NN*KK), out + (size_t)xoutc[t]*NN);
  }

  // ---- layer 5 (1x1 conv 513 -> 1024, fused BN stats) + global pooling ----
  k_conv5g<<<dim3(1024/64, NN/128, BB), 256, 0, stream>>>(out + (size_t)2051*NN, w5t, y5, s1b, s2b);
  k_final5_v2<<<dim3(1024, BB), 256, 0, stream>>>(y5, s1b, s2b, Gp[4], Bp[4], out);
}